// Round 1
// baseline (433.364 us; speedup 1.0000x reference)
//
#include <hip/hip_runtime.h>
#include <hip/hip_bf16.h>
#include <math.h>

#define T_TOT 4160
#define H_N   8
#define NWTOK 64
#define TFEA  4096

// ---------------------------------------------------------------------------
// K1: qkv = x @ W_qkv + b_qkv, scattered into head layout (BH, T, 64).
// Q scaled by 0.125 (Dh^-0.5). M=8320, N=1536, K=512. fp32 tiled GEMM.
// ---------------------------------------------------------------------------
__global__ __launch_bounds__(256) void qkv_gemm(
    const float* __restrict__ X, const float* __restrict__ W,
    const float* __restrict__ bqkv,
    float* __restrict__ Q, float* __restrict__ Kh, float* __restrict__ Vh) {
  __shared__ float As[64][17];
  __shared__ float Bs[16][64];
  const int m0 = blockIdx.x * 64;
  const int n0 = blockIdx.y * 64;
  const int tid = threadIdx.x;
  const int tn = tid & 15, tm = tid >> 4;
  float acc[4][4] = {};
  for (int k0 = 0; k0 < 512; k0 += 16) {
    {
      int e = tid * 4;
      int r = e >> 4, c = e & 15;
      const float4 a = *reinterpret_cast<const float4*>(&X[(m0 + r) * 512 + k0 + c]);
      As[r][c] = a.x; As[r][c + 1] = a.y; As[r][c + 2] = a.z; As[r][c + 3] = a.w;
    }
    {
      int e = tid * 4;
      int r = e >> 6, c = e & 63;
      *reinterpret_cast<float4*>(&Bs[r][c]) =
          *reinterpret_cast<const float4*>(&W[(k0 + r) * 1536 + n0 + c]);
    }
    __syncthreads();
#pragma unroll
    for (int kk = 0; kk < 16; ++kk) {
      float a[4];
#pragma unroll
      for (int i = 0; i < 4; ++i) a[i] = As[tm * 4 + i][kk];
      const float4 bv = *reinterpret_cast<const float4*>(&Bs[kk][tn * 4]);
      const float b[4] = {bv.x, bv.y, bv.z, bv.w};
#pragma unroll
      for (int i = 0; i < 4; ++i)
#pragma unroll
        for (int j = 0; j < 4; ++j) acc[i][j] += a[i] * b[j];
    }
    __syncthreads();
  }
#pragma unroll
  for (int i = 0; i < 4; ++i) {
    const int m = m0 + tm * 4 + i;
    const int bb = m / T_TOT, t = m % T_TOT;
#pragma unroll
    for (int j = 0; j < 4; ++j) {
      const int nn = n0 + tn * 4 + j;
      float v = acc[i][j] + bqkv[nn];
      const int which = nn >> 9;      // 0=Q 1=K 2=V
      const int e = nn & 511;
      const int h = e >> 6, d = e & 63;
      const int idx = ((bb * H_N + h) * T_TOT + t) * 64 + d;
      if (which == 0)      Q[idx]  = v * 0.125f;
      else if (which == 1) Kh[idx] = v;
      else                 Vh[idx] = v;
    }
  }
}

// ---------------------------------------------------------------------------
// K2: wtok global attention. One wave per (bh, n). 65 candidates:
// c=0 -> Kw[n] (token n); c>=1 -> Kf[n*64 + c-1] (token 64 + n*64 + c-1).
// Softmax over 65, output = sum aw_c * V_c. Writes OW and AO[token n].
// ---------------------------------------------------------------------------
__global__ __launch_bounds__(64) void wtok_attn(
    const float* __restrict__ Q, const float* __restrict__ Kh,
    const float* __restrict__ Vh,
    float* __restrict__ OW, float* __restrict__ AO) {
  const int bh = blockIdx.x >> 6;
  const int n = blockIdx.x & 63;
  const int lane = threadIdx.x;
  __shared__ float q[64];
  __shared__ float sc[65];
  __shared__ float aw[65];
  const int base = bh * T_TOT * 64;
  q[lane] = Q[base + n * 64 + lane];
  __syncthreads();
  for (int c = lane; c < 65; c += 64) {
    const float* krow = (c == 0) ? &Kh[base + n * 64]
                                 : &Kh[base + (NWTOK + n * 64 + (c - 1)) * 64];
    float acc = 0.f;
#pragma unroll
    for (int d = 0; d < 64; ++d) acc += q[d] * krow[d];
    sc[c] = acc;
  }
  __syncthreads();
  const float v = sc[lane];
  float mx = fmaxf(v, sc[64]);
#pragma unroll
  for (int off = 32; off >= 1; off >>= 1) mx = fmaxf(mx, __shfl_xor(mx, off));
  const float e = expf(v - mx);
  const float e64 = expf(sc[64] - mx);
  float sum = e + (lane == 0 ? e64 : 0.f);
#pragma unroll
  for (int off = 32; off >= 1; off >>= 1) sum += __shfl_xor(sum, off);
  const float inv = 1.f / sum;
  aw[lane] = e * inv;
  if (lane == 0) aw[64] = e64 * inv;
  __syncthreads();
  float o = 0.f;
  for (int c = 0; c < 65; ++c) {
    const float* vrow = (c == 0) ? &Vh[base + n * 64]
                                 : &Vh[base + (NWTOK + n * 64 + (c - 1)) * 64];
    o += aw[c] * vrow[lane];
  }
  OW[(bh * 64 + n) * 64 + lane] = o;
  AO[base + n * 64 + lane] = o;
}

// ---------------------------------------------------------------------------
// K3: feature local attention. One wave per (bh, chunk n); lane = token in
// chunk. 18 keys: summary (out_wtok[n], chunk-softmaxed across the wave) +
// 17-wide zero-padded sliding window (NOT masked: zero keys score 0 and stay
// in the softmax denominator, matching the reference's jnp.pad).
// LDS rows padded to stride 65 -> only 2-way bank conflicts (free).
// ---------------------------------------------------------------------------
__global__ __launch_bounds__(64) void fea_attn(
    const float* __restrict__ Q, const float* __restrict__ Kh,
    const float* __restrict__ Vh, const float* __restrict__ OW,
    float* __restrict__ AO) {
  const int bh = blockIdx.x >> 6;
  const int n = blockIdx.x & 63;
  const int t = threadIdx.x;
  __shared__ float Ks[80 * 65];
  __shared__ float Vs[80 * 65];
  __shared__ float Qs[64 * 65];
  __shared__ float ow[64];
  const int base = bh * T_TOT * 64;
  const int tok0 = n * 64;  // chunk start in feature space
  for (int j = 0; j < 80; ++j) {
    const int tok = tok0 - 8 + j;
    float kv = 0.f, vv = 0.f;
    if (tok >= 0 && tok < TFEA) {
      kv = Kh[base + (NWTOK + tok) * 64 + t];
      vv = Vh[base + (NWTOK + tok) * 64 + t];
    }
    Ks[j * 65 + t] = kv;
    Vs[j * 65 + t] = vv;
  }
  for (int j = 0; j < 64; ++j)
    Qs[j * 65 + t] = Q[base + (NWTOK + tok0 + j) * 64 + t];
  ow[t] = OW[(bh * 64 + n) * 64 + t];
  __syncthreads();
  // summary score
  float s0 = 0.f;
#pragma unroll
  for (int d = 0; d < 64; ++d) s0 += Qs[t * 65 + d] * ow[d];
  // 17 local scores
  float p[17];
  float m = -1e30f;
#pragma unroll
  for (int w = 0; w < 17; ++w) {
    float acc = 0.f;
#pragma unroll
    for (int d = 0; d < 64; ++d) acc += Qs[t * 65 + d] * Ks[(t + w) * 65 + d];
    p[w] = acc;
    m = fmaxf(m, acc);
  }
  float sum = 0.f;
#pragma unroll
  for (int w = 0; w < 17; ++w) { p[w] = expf(p[w] - m); sum += p[w]; }
  const float inv = 1.f / sum;
#pragma unroll
  for (int w = 0; w < 17; ++w) p[w] *= inv;
  // chunk softmax of s0 across the wave (chunk == 64 == wave size)
  float mx = s0;
#pragma unroll
  for (int off = 32; off >= 1; off >>= 1) mx = fmaxf(mx, __shfl_xor(mx, off));
  const float e0 = expf(s0 - mx);
  float es = e0;
#pragma unroll
  for (int off = 32; off >= 1; off >>= 1) es += __shfl_xor(es, off);
  const float w0 = e0 / es;
  // output; reuse Qs (each lane only touches its own row) then coalesced store
  for (int d = 0; d < 64; ++d) {
    float acc = w0 * ow[d];
#pragma unroll
    for (int w = 0; w < 17; ++w) acc += p[w] * Vs[(t + w) * 65 + d];
    Qs[t * 65 + d] = acc;
  }
  __syncthreads();
  for (int j = 0; j < 64; ++j)
    AO[base + (NWTOK + tok0 + j) * 64 + t] = Qs[j * 65 + t];
}

// ---------------------------------------------------------------------------
// K4: out = AO(head-merged) @ W_out + b_out. M=8320, N=512, K=512.
// A gathered from head layout: k = h*64+d -> AO[((b*8+h)*T + t)*64 + d].
// ---------------------------------------------------------------------------
__global__ __launch_bounds__(256) void out_gemm(
    const float* __restrict__ AO, const float* __restrict__ W,
    const float* __restrict__ bo, float* __restrict__ OUT) {
  __shared__ float As[64][17];
  __shared__ float Bs[16][64];
  const int m0 = blockIdx.x * 64;
  const int n0 = blockIdx.y * 64;
  const int tid = threadIdx.x;
  const int tn = tid & 15, tm = tid >> 4;
  float acc[4][4] = {};
  for (int k0 = 0; k0 < 512; k0 += 16) {
    {
      int e = tid * 4;
      int r = e >> 4, c = e & 15;
      const int m = m0 + r;
      const int bb = m / T_TOT, t = m % T_TOT;
      const int k = k0 + c;
      const int h = k >> 6, d = k & 63;
      const float4 a = *reinterpret_cast<const float4*>(
          &AO[((bb * H_N + h) * T_TOT + t) * 64 + d]);
      As[r][c] = a.x; As[r][c + 1] = a.y; As[r][c + 2] = a.z; As[r][c + 3] = a.w;
    }
    {
      int e = tid * 4;
      int r = e >> 6, c = e & 63;
      *reinterpret_cast<float4*>(&Bs[r][c]) =
          *reinterpret_cast<const float4*>(&W[(k0 + r) * 512 + n0 + c]);
    }
    __syncthreads();
#pragma unroll
    for (int kk = 0; kk < 16; ++kk) {
      float a[4];
#pragma unroll
      for (int i = 0; i < 4; ++i) a[i] = As[tm * 4 + i][kk];
      const float4 bv = *reinterpret_cast<const float4*>(&Bs[kk][tn * 4]);
      const float b[4] = {bv.x, bv.y, bv.z, bv.w};
#pragma unroll
      for (int i = 0; i < 4; ++i)
#pragma unroll
        for (int j = 0; j < 4; ++j) acc[i][j] += a[i] * b[j];
    }
    __syncthreads();
  }
#pragma unroll
  for (int i = 0; i < 4; ++i) {
    const int m = m0 + tm * 4 + i;
    const int nn = n0 + tn * 4;
    float4 o;
    o.x = acc[i][0] + bo[nn];
    o.y = acc[i][1] + bo[nn + 1];
    o.z = acc[i][2] + bo[nn + 2];
    o.w = acc[i][3] + bo[nn + 3];
    *reinterpret_cast<float4*>(&OUT[m * 512 + nn]) = o;
  }
}

extern "C" void kernel_launch(void* const* d_in, const int* in_sizes, int n_in,
                              void* d_out, int out_size, void* d_ws, size_t ws_size,
                              hipStream_t stream) {
  const float* x    = (const float*)d_in[0];
  const float* Wqkv = (const float*)d_in[1];
  const float* bqkv = (const float*)d_in[2];
  const float* Wout = (const float*)d_in[3];
  const float* bout = (const float*)d_in[4];
  float* out = (float*)d_out;

  float* ws = (float*)d_ws;
  const size_t SZ = (size_t)16 * T_TOT * 64;  // 4,259,840 floats per buffer
  float* Q  = ws;
  float* Kh = ws + SZ;
  float* Vh = ws + 2 * SZ;
  float* AO = ws + 3 * SZ;
  float* OW = ws + 4 * SZ;

  qkv_gemm<<<dim3(130, 24), 256, 0, stream>>>(x, Wqkv, bqkv, Q, Kh, Vh);
  wtok_attn<<<1024, 64, 0, stream>>>(Q, Kh, Vh, OW, AO);
  fea_attn<<<1024, 64, 0, stream>>>(Q, Kh, Vh, OW, AO);
  out_gemm<<<dim3(130, 8), 256, 0, stream>>>(AO, Wout, bout, out);
}

// Round 5
// 210.606 us; speedup vs baseline: 2.0577x; 2.0577x over previous
//
#include <hip/hip_runtime.h>
#include <hip/hip_bf16.h>
#include <math.h>

#define T_TOT 4160
#define H_N   8
#define NWTOK 64
#define TFEA  4096

typedef __bf16 bf16x8 __attribute__((ext_vector_type(8)));
typedef float  f32x4  __attribute__((ext_vector_type(4)));

__device__ inline ushort f2b(float f) {
  __hip_bfloat16 h = __float2bfloat16(f);
  return *reinterpret_cast<ushort*>(&h);
}

// ---------------------------------------------------------------------------
// conv_x: fp32 -> bf16, linear. 8 elems/thread, 16B stores.
// ---------------------------------------------------------------------------
__global__ __launch_bounds__(256) void conv_x(
    const float* __restrict__ X, ushort* __restrict__ Xb, int n8) {
  const int i = blockIdx.x * 256 + threadIdx.x;
  if (i >= n8) return;
  const float4 a = reinterpret_cast<const float4*>(X)[i * 2];
  const float4 b = reinterpret_cast<const float4*>(X)[i * 2 + 1];
  union { ushort u[8]; uint4 v; } r;
  r.u[0] = f2b(a.x); r.u[1] = f2b(a.y); r.u[2] = f2b(a.z); r.u[3] = f2b(a.w);
  r.u[4] = f2b(b.x); r.u[5] = f2b(b.y); r.u[6] = f2b(b.z); r.u[7] = f2b(b.w);
  reinterpret_cast<uint4*>(Xb)[i] = r.v;
}

// ---------------------------------------------------------------------------
// conv_wT: W [R][C] fp32 -> WT [C][R] bf16 (LDS 64x64 tiled transpose).
// ---------------------------------------------------------------------------
__global__ __launch_bounds__(256) void conv_wT(
    const float* __restrict__ W, ushort* __restrict__ WT, int R, int C) {
  __shared__ float tile[64][65];
  const int r0 = blockIdx.x * 64, c0 = blockIdx.y * 64;
  const int tid = threadIdx.x;
  const int rr = tid >> 4, c4 = (tid & 15) * 4;
#pragma unroll
  for (int q = 0; q < 4; ++q) {
    const int r = q * 16 + rr;
    const float4 v = *reinterpret_cast<const float4*>(&W[(size_t)(r0 + r) * C + c0 + c4]);
    tile[r][c4] = v.x; tile[r][c4 + 1] = v.y; tile[r][c4 + 2] = v.z; tile[r][c4 + 3] = v.w;
  }
  __syncthreads();
#pragma unroll
  for (int q = 0; q < 4; ++q) {
    const int cr = q * 16 + rr;  // row of WT = original column
    ushort4 o;
    o.x = f2b(tile[c4][cr]);
    o.y = f2b(tile[c4 + 1][cr]);
    o.z = f2b(tile[c4 + 2][cr]);
    o.w = f2b(tile[c4 + 3][cr]);
    *reinterpret_cast<ushort4*>(&WT[(size_t)(c0 + cr) * R + r0 + c4]) = o;
  }
}

// ---------------------------------------------------------------------------
// gemm_mfma: C[M x N] = A[M x 512] * BT[N x 512]^T, bf16 in, f32 accum.
// m97 structure: 128x128 tile, BK=64, 4 waves (2x2), 16x16x32 bf16 MFMA,
// global_load_lds width-16 staging, T2 XOR swizzle via pre-swizzled global
// source (rule #21: linear LDS dest + inverse-swz source + swz read).
// MODE 0: qkv epilogue (bias, Q-scale, head-layout scatter to O0/O1/O2).
// MODE 1: out epilogue (bias, O0[m*512+n]).
// ---------------------------------------------------------------------------
template<int MODE>
__global__ __launch_bounds__(256) void gemm_mfma(
    const ushort* __restrict__ A, const ushort* __restrict__ BT,
    const float* __restrict__ bias, float* __restrict__ O0,
    float* __restrict__ O1, float* __restrict__ O2) {
  __shared__ ushort sA[128 * 64];
  __shared__ ushort sB[128 * 64];
  const int tid = threadIdx.x;
  const int lane = tid & 63, wave = tid >> 6;
  const int m0 = blockIdx.x * 128, n0 = blockIdx.y * 128;
  const int wm = wave >> 1, wn = wave & 1;

  f32x4 acc[4][4] = {};

  auto stage = [&](int kt) {
    const ushort* Ag = A + (size_t)m0 * 512 + kt * 64;
    const ushort* Bg = BT + (size_t)n0 * 512 + kt * 64;
#pragma unroll
    for (int r = 0; r < 4; ++r) {
      const int rowbase = r * 32 + wave * 8;       // wave-uniform
      const int row = rowbase + (lane >> 3);
      const int c = lane & 7;
      const int cc = c ^ (row & 7);                // inverse-swizzled source
      __builtin_amdgcn_global_load_lds(
          (const __attribute__((address_space(1))) void*)(Ag + (size_t)row * 512 + cc * 8),
          (__attribute__((address_space(3))) void*)(sA + rowbase * 64), 16, 0, 0);
      __builtin_amdgcn_global_load_lds(
          (const __attribute__((address_space(1))) void*)(Bg + (size_t)row * 512 + cc * 8),
          (__attribute__((address_space(3))) void*)(sB + rowbase * 64), 16, 0, 0);
    }
  };

  stage(0);
  for (int kt = 0; kt < 8; ++kt) {
    __syncthreads();   // drains vmcnt -> tiles ready
#pragma unroll
    for (int ks = 0; ks < 2; ++ks) {
      bf16x8 af[4], bfr[4];
      const int cc = ks * 4 + (lane >> 4);
      const int rA = wm * 64 + (lane & 15);
      const int rB = wn * 64 + (lane & 15);
#pragma unroll
      for (int i = 0; i < 4; ++i) {
        const int ra = rA + i * 16;
        af[i] = *reinterpret_cast<const bf16x8*>(&sA[ra * 64 + ((cc ^ (ra & 7)) << 3)]);
        const int rb = rB + i * 16;
        bfr[i] = *reinterpret_cast<const bf16x8*>(&sB[rb * 64 + ((cc ^ (rb & 7)) << 3)]);
      }
#pragma unroll
      for (int i = 0; i < 4; ++i)
#pragma unroll
        for (int j = 0; j < 4; ++j)
          acc[i][j] = __builtin_amdgcn_mfma_f32_16x16x32_bf16(af[i], bfr[j], acc[i][j], 0, 0, 0);
    }
    __syncthreads();   // all waves done reading before overwrite
    if (kt < 7) stage(kt + 1);
  }

#pragma unroll
  for (int i = 0; i < 4; ++i) {
#pragma unroll
    for (int j = 0; j < 4; ++j) {
      const f32x4 a = acc[i][j];
      const int n = n0 + wn * 64 + j * 16 + (lane & 15);
      const float bv = bias[n];
#pragma unroll
      for (int r = 0; r < 4; ++r) {
        const int m = m0 + wm * 64 + i * 16 + ((lane >> 4) << 2) + r;
        const float v = a[r] + bv;
        if (MODE == 0) {
          const int bb = m / T_TOT, t = m - bb * T_TOT;
          const int which = n >> 9, e = n & 511;
          const int h = e >> 6, d = e & 63;
          const size_t idx = ((size_t)(bb * H_N + h) * T_TOT + t) * 64 + d;
          if (which == 0)      O0[idx] = v * 0.125f;
          else if (which == 1) O1[idx] = v;
          else                 O2[idx] = v;
        } else {
          O0[(size_t)m * 512 + n] = v;
        }
      }
    }
  }
}

// ---------------------------------------------------------------------------
// K2: wtok global attention (unchanged math; AO now bf16 merged layout).
// ---------------------------------------------------------------------------
__global__ __launch_bounds__(64) void wtok_attn(
    const float* __restrict__ Q, const float* __restrict__ Kh,
    const float* __restrict__ Vh,
    float* __restrict__ OW, ushort* __restrict__ AObf) {
  const int bh = blockIdx.x >> 6;
  const int n = blockIdx.x & 63;
  const int lane = threadIdx.x;
  __shared__ float q[64];
  __shared__ float sc[65];
  __shared__ float aw[65];
  const int base = bh * T_TOT * 64;
  q[lane] = Q[base + n * 64 + lane];
  __syncthreads();
  for (int c = lane; c < 65; c += 64) {
    const float* krow = (c == 0) ? &Kh[base + n * 64]
                                 : &Kh[base + (NWTOK + n * 64 + (c - 1)) * 64];
    float acc = 0.f;
#pragma unroll
    for (int d = 0; d < 64; ++d) acc += q[d] * krow[d];
    sc[c] = acc;
  }
  __syncthreads();
  const float v = sc[lane];
  float mx = fmaxf(v, sc[64]);
#pragma unroll
  for (int off = 32; off >= 1; off >>= 1) mx = fmaxf(mx, __shfl_xor(mx, off));
  const float e = expf(v - mx);
  const float e64 = expf(sc[64] - mx);
  float sum = e + (lane == 0 ? e64 : 0.f);
#pragma unroll
  for (int off = 32; off >= 1; off >>= 1) sum += __shfl_xor(sum, off);
  const float inv = 1.f / sum;
  aw[lane] = e * inv;
  if (lane == 0) aw[64] = e64 * inv;
  __syncthreads();
  float o = 0.f;
  for (int c = 0; c < 65; ++c) {
    const float* vrow = (c == 0) ? &Vh[base + n * 64]
                                 : &Vh[base + (NWTOK + n * 64 + (c - 1)) * 64];
    o += aw[c] * vrow[lane];
  }
  OW[(bh * 64 + n) * 64 + lane] = o;
  const int bb = bh >> 3, h = bh & 7;
  AObf[((size_t)bb * T_TOT + n) * 512 + h * 64 + lane] = f2b(o);
}

// ---------------------------------------------------------------------------
// K3: feature local attention (unchanged math; AO now bf16 merged layout).
// ---------------------------------------------------------------------------
__global__ __launch_bounds__(64) void fea_attn(
    const float* __restrict__ Q, const float* __restrict__ Kh,
    const float* __restrict__ Vh, const float* __restrict__ OW,
    ushort* __restrict__ AObf) {
  const int bh = blockIdx.x >> 6;
  const int n = blockIdx.x & 63;
  const int t = threadIdx.x;
  __shared__ float Ks[80 * 65];
  __shared__ float Vs[80 * 65];
  __shared__ float Qs[64 * 65];
  __shared__ float ow[64];
  const int base = bh * T_TOT * 64;
  const int tok0 = n * 64;
  for (int j = 0; j < 80; ++j) {
    const int tok = tok0 - 8 + j;
    float kv = 0.f, vv = 0.f;
    if (tok >= 0 && tok < TFEA) {
      kv = Kh[base + (NWTOK + tok) * 64 + t];
      vv = Vh[base + (NWTOK + tok) * 64 + t];
    }
    Ks[j * 65 + t] = kv;
    Vs[j * 65 + t] = vv;
  }
  for (int j = 0; j < 64; ++j)
    Qs[j * 65 + t] = Q[base + (NWTOK + tok0 + j) * 64 + t];
  ow[t] = OW[(bh * 64 + n) * 64 + t];
  __syncthreads();
  float s0 = 0.f;
#pragma unroll
  for (int d = 0; d < 64; ++d) s0 += Qs[t * 65 + d] * ow[d];
  float p[17];
  float m = -1e30f;
#pragma unroll
  for (int w = 0; w < 17; ++w) {
    float acc = 0.f;
#pragma unroll
    for (int d = 0; d < 64; ++d) acc += Qs[t * 65 + d] * Ks[(t + w) * 65 + d];
    p[w] = acc;
    m = fmaxf(m, acc);
  }
  float sum = 0.f;
#pragma unroll
  for (int w = 0; w < 17; ++w) { p[w] = expf(p[w] - m); sum += p[w]; }
  const float inv = 1.f / sum;
#pragma unroll
  for (int w = 0; w < 17; ++w) p[w] *= inv;
  float mx = s0;
#pragma unroll
  for (int off = 32; off >= 1; off >>= 1) mx = fmaxf(mx, __shfl_xor(mx, off));
  const float e0 = expf(s0 - mx);
  float es = e0;
#pragma unroll
  for (int off = 32; off >= 1; off >>= 1) es += __shfl_xor(es, off);
  const float w0 = e0 / es;
  for (int d = 0; d < 64; ++d) {
    float acc = w0 * ow[d];
#pragma unroll
    for (int w = 0; w < 17; ++w) acc += p[w] * Vs[(t + w) * 65 + d];
    Qs[t * 65 + d] = acc;
  }
  __syncthreads();
  const int bb = bh >> 3, h = bh & 7;
  for (int j = 0; j < 64; ++j)
    AObf[((size_t)bb * T_TOT + NWTOK + tok0 + j) * 512 + h * 64 + t] =
        f2b(Qs[j * 65 + t]);
}

extern "C" void kernel_launch(void* const* d_in, const int* in_sizes, int n_in,
                              void* d_out, int out_size, void* d_ws, size_t ws_size,
                              hipStream_t stream) {
  const float* x    = (const float*)d_in[0];
  const float* Wqkv = (const float*)d_in[1];
  const float* bqkv = (const float*)d_in[2];
  const float* Wout = (const float*)d_in[3];
  const float* bout = (const float*)d_in[4];
  float* out = (float*)d_out;

  const size_t SZ = (size_t)16 * T_TOT * 64;  // 4,259,840
  float* wsf = (float*)d_ws;
  float* Q   = wsf;
  float* Kh  = Q + SZ;
  float* Vh  = Kh + SZ;
  float* OW  = Vh + SZ;                       // 65,536 floats
  ushort* Xb    = (ushort*)(OW + 65536);      // 8320*512 bf16
  ushort* WqkvT = Xb + SZ;                    // 1536*512 bf16
  ushort* WoutT = WqkvT + (size_t)1536 * 512; // 512*512 bf16
  ushort* AObf  = WoutT + (size_t)512 * 512;  // 8320*512 bf16

  conv_x<<<2080, 256, 0, stream>>>(x, Xb, (int)(SZ / 8));
  conv_wT<<<dim3(8, 24), 256, 0, stream>>>(Wqkv, WqkvT, 512, 1536);
  conv_wT<<<dim3(8, 8), 256, 0, stream>>>(Wout, WoutT, 512, 512);
  gemm_mfma<0><<<dim3(65, 12), 256, 0, stream>>>(Xb, WqkvT, bqkv, Q, Kh, Vh);
  wtok_attn<<<1024, 64, 0, stream>>>(Q, Kh, Vh, OW, AObf);
  fea_attn<<<1024, 64, 0, stream>>>(Q, Kh, Vh, OW, AObf);
  gemm_mfma<1><<<dim3(65, 4), 256, 0, stream>>>(AObf, WoutT, bout, out, nullptr, nullptr);
}

// Round 8
// 143.237 us; speedup vs baseline: 3.0255x; 1.4703x over previous
//
#include <hip/hip_runtime.h>
#include <hip/hip_bf16.h>
#include <math.h>

#define T_TOT 4160
#define H_N   8
#define NWTOK 64
#define TFEA  4096

typedef __bf16 bf16x8 __attribute__((ext_vector_type(8)));
typedef float  f32x4  __attribute__((ext_vector_type(4)));

__device__ inline ushort f2b(float f) {
  __hip_bfloat16 h = __float2bfloat16(f);
  return *reinterpret_cast<ushort*>(&h);
}
__device__ inline float b2f(ushort u) {
  union { uint i; float v; } a;
  a.i = ((uint)u) << 16;
  return a.v;
}
__device__ inline uint pk2(float a, float b) {
  return (uint)f2b(a) | ((uint)f2b(b) << 16);
}
// unpack 8 bf16 (uint4) -> 8 f32
__device__ inline void unpack8(uint4 u, float* f) {
  union { uint i; float v; } a;
  a.i = u.x << 16;        f[0] = a.v;
  a.i = u.x & 0xffff0000u; f[1] = a.v;
  a.i = u.y << 16;        f[2] = a.v;
  a.i = u.y & 0xffff0000u; f[3] = a.v;
  a.i = u.z << 16;        f[4] = a.v;
  a.i = u.z & 0xffff0000u; f[5] = a.v;
  a.i = u.w << 16;        f[6] = a.v;
  a.i = u.w & 0xffff0000u; f[7] = a.v;
}

// ---------------------------------------------------------------------------
// conv_x: fp32 -> bf16, linear. 8 elems/thread, 16B stores.
// ---------------------------------------------------------------------------
__global__ __launch_bounds__(256) void conv_x(
    const float* __restrict__ X, ushort* __restrict__ Xb, int n8) {
  const int i = blockIdx.x * 256 + threadIdx.x;
  if (i >= n8) return;
  const float4 a = reinterpret_cast<const float4*>(X)[i * 2];
  const float4 b = reinterpret_cast<const float4*>(X)[i * 2 + 1];
  union { ushort u[8]; uint4 v; } r;
  r.u[0] = f2b(a.x); r.u[1] = f2b(a.y); r.u[2] = f2b(a.z); r.u[3] = f2b(a.w);
  r.u[4] = f2b(b.x); r.u[5] = f2b(b.y); r.u[6] = f2b(b.z); r.u[7] = f2b(b.w);
  reinterpret_cast<uint4*>(Xb)[i] = r.v;
}

// ---------------------------------------------------------------------------
// conv_wT: W [R][C] fp32 -> WT [C][R] bf16 (LDS 64x64 tiled transpose).
// ---------------------------------------------------------------------------
__global__ __launch_bounds__(256) void conv_wT(
    const float* __restrict__ W, ushort* __restrict__ WT, int R, int C) {
  __shared__ float tile[64][65];
  const int r0 = blockIdx.x * 64, c0 = blockIdx.y * 64;
  const int tid = threadIdx.x;
  const int rr = tid >> 4, c4 = (tid & 15) * 4;
#pragma unroll
  for (int q = 0; q < 4; ++q) {
    const int r = q * 16 + rr;
    const float4 v = *reinterpret_cast<const float4*>(&W[(size_t)(r0 + r) * C + c0 + c4]);
    tile[r][c4] = v.x; tile[r][c4 + 1] = v.y; tile[r][c4 + 2] = v.z; tile[r][c4 + 3] = v.w;
  }
  __syncthreads();
#pragma unroll
  for (int q = 0; q < 4; ++q) {
    const int cr = q * 16 + rr;
    ushort4 o;
    o.x = f2b(tile[c4][cr]);
    o.y = f2b(tile[c4 + 1][cr]);
    o.z = f2b(tile[c4 + 2][cr]);
    o.w = f2b(tile[c4 + 3][cr]);
    *reinterpret_cast<ushort4*>(&WT[(size_t)(c0 + cr) * R + r0 + c4]) = o;
  }
}

// ---------------------------------------------------------------------------
// gemm_mfma: C[M x N] = A[M x 512] * BT[N x 512]^T, bf16 in, f32 accum.
// 128x128 tile, BK=64, 4 waves, 16x16x32 bf16 MFMA, global_load_lds staging,
// T2 XOR swizzle (linear LDS dest + inverse-swz global source + swz read).
// MODE 0: qkv epilogue -> bf16 Q/K/V in head layout (Q scaled).
// MODE 1: out epilogue -> f32 O0[m*512+n].
// ---------------------------------------------------------------------------
template<int MODE>
__global__ __launch_bounds__(256) void gemm_mfma(
    const ushort* __restrict__ A, const ushort* __restrict__ BT,
    const float* __restrict__ bias, void* __restrict__ O0v,
    void* __restrict__ O1v, void* __restrict__ O2v) {
  __shared__ ushort sA[128 * 64];
  __shared__ ushort sB[128 * 64];
  const int tid = threadIdx.x;
  const int lane = tid & 63, wave = tid >> 6;
  const int m0 = blockIdx.x * 128, n0 = blockIdx.y * 128;
  const int wm = wave >> 1, wn = wave & 1;

  f32x4 acc[4][4] = {};

  auto stage = [&](int kt) {
    const ushort* Ag = A + (size_t)m0 * 512 + kt * 64;
    const ushort* Bg = BT + (size_t)n0 * 512 + kt * 64;
#pragma unroll
    for (int r = 0; r < 4; ++r) {
      const int rowbase = r * 32 + wave * 8;
      const int row = rowbase + (lane >> 3);
      const int c = lane & 7;
      const int cc = c ^ (row & 7);
      __builtin_amdgcn_global_load_lds(
          (const __attribute__((address_space(1))) void*)(Ag + (size_t)row * 512 + cc * 8),
          (__attribute__((address_space(3))) void*)(sA + rowbase * 64), 16, 0, 0);
      __builtin_amdgcn_global_load_lds(
          (const __attribute__((address_space(1))) void*)(Bg + (size_t)row * 512 + cc * 8),
          (__attribute__((address_space(3))) void*)(sB + rowbase * 64), 16, 0, 0);
    }
  };

  stage(0);
  for (int kt = 0; kt < 8; ++kt) {
    __syncthreads();
#pragma unroll
    for (int ks = 0; ks < 2; ++ks) {
      bf16x8 af[4], bfr[4];
      const int cc = ks * 4 + (lane >> 4);
      const int rA = wm * 64 + (lane & 15);
      const int rB = wn * 64 + (lane & 15);
#pragma unroll
      for (int i = 0; i < 4; ++i) {
        const int ra = rA + i * 16;
        af[i] = *reinterpret_cast<const bf16x8*>(&sA[ra * 64 + ((cc ^ (ra & 7)) << 3)]);
        const int rb = rB + i * 16;
        bfr[i] = *reinterpret_cast<const bf16x8*>(&sB[rb * 64 + ((cc ^ (rb & 7)) << 3)]);
      }
#pragma unroll
      for (int i = 0; i < 4; ++i)
#pragma unroll
        for (int j = 0; j < 4; ++j)
          acc[i][j] = __builtin_amdgcn_mfma_f32_16x16x32_bf16(af[i], bfr[j], acc[i][j], 0, 0, 0);
    }
    __syncthreads();
    if (kt < 7) stage(kt + 1);
  }

#pragma unroll
  for (int i = 0; i < 4; ++i) {
#pragma unroll
    for (int j = 0; j < 4; ++j) {
      const f32x4 a = acc[i][j];
      const int n = n0 + wn * 64 + j * 16 + (lane & 15);
      const float bv = bias[n];
#pragma unroll
      for (int r = 0; r < 4; ++r) {
        const int m = m0 + wm * 64 + i * 16 + ((lane >> 4) << 2) + r;
        const float v = a[r] + bv;
        if (MODE == 0) {
          const int bb = m / T_TOT, t = m - bb * T_TOT;
          const int which = n >> 9, e = n & 511;
          const int h = e >> 6, d = e & 63;
          const size_t idx = ((size_t)(bb * H_N + h) * T_TOT + t) * 64 + d;
          if (which == 0)      ((ushort*)O0v)[idx] = f2b(v * 0.125f);
          else if (which == 1) ((ushort*)O1v)[idx] = f2b(v);
          else                 ((ushort*)O2v)[idx] = f2b(v);
        } else {
          ((float*)O0v)[(size_t)m * 512 + n] = v;
        }
      }
    }
  }
}

// ---------------------------------------------------------------------------
// K2: wtok global attention, bf16 K/V/Q loads. One wave per (bh, n).
// ---------------------------------------------------------------------------
__global__ __launch_bounds__(64) void wtok_attn(
    const ushort* __restrict__ Qb, const ushort* __restrict__ Kb,
    const ushort* __restrict__ Vb,
    float* __restrict__ OW, ushort* __restrict__ AObf) {
  const int bh = blockIdx.x >> 6;
  const int n = blockIdx.x & 63;
  const int lane = threadIdx.x;
  __shared__ float q[64];
  __shared__ float sc[65];
  __shared__ float aw[65];
  const size_t base = (size_t)bh * T_TOT * 64;
  q[lane] = b2f(Qb[base + n * 64 + lane]);
  __syncthreads();
  for (int c = lane; c < 65; c += 64) {
    const ushort* krow = (c == 0) ? &Kb[base + n * 64]
                                  : &Kb[base + (size_t)(NWTOK + n * 64 + (c - 1)) * 64];
    float acc = 0.f;
#pragma unroll
    for (int d0 = 0; d0 < 8; ++d0) {
      const uint4 u4 = *reinterpret_cast<const uint4*>(&krow[d0 * 8]);
      float f[8]; unpack8(u4, f);
#pragma unroll
      for (int k = 0; k < 8; ++k) acc += q[d0 * 8 + k] * f[k];
    }
    sc[c] = acc;
  }
  __syncthreads();
  const float v = sc[lane];
  float mx = fmaxf(v, sc[64]);
#pragma unroll
  for (int off = 32; off >= 1; off >>= 1) mx = fmaxf(mx, __shfl_xor(mx, off));
  const float e = __expf(v - mx);
  const float e64 = __expf(sc[64] - mx);
  float sum = e + (lane == 0 ? e64 : 0.f);
#pragma unroll
  for (int off = 32; off >= 1; off >>= 1) sum += __shfl_xor(sum, off);
  const float inv = 1.f / sum;
  aw[lane] = e * inv;
  if (lane == 0) aw[64] = e64 * inv;
  __syncthreads();
  float o = 0.f;
  for (int c = 0; c < 65; ++c) {
    const ushort* vrow = (c == 0) ? &Vb[base + n * 64]
                                  : &Vb[base + (size_t)(NWTOK + n * 64 + (c - 1)) * 64];
    o += aw[c] * b2f(vrow[lane]);
  }
  OW[(bh * 64 + n) * 64 + lane] = o;
  AObf[((size_t)(bh >> 3) * T_TOT + n) * 512 + (bh & 7) * 64 + lane] = f2b(o);
}

// ---------------------------------------------------------------------------
// K3: feature local attention, restructured for occupancy:
//  - 256 threads = 4 waves; wave wv owns d-quarter [16wv, 16wv+16)
//  - K/V staged bf16 in LDS (80 rows x 64), XOR-swizzled in 16B units
//    (both-sides swizzle; b128 reads hit the 8-way hardware floor)
//  - Q in registers (16 f32/lane), output written as packed bf16 uint4
//  - partial scores combined via ps[4][18][64] (w=17 is the summary score)
// LDS total ~39.2 KB -> 4 blocks/CU x 4 waves = 16 waves/CU.
// Zero-padded window semantics preserved (pad rows stage zeros, stay in
// the softmax denominator).
// ---------------------------------------------------------------------------
__global__ __launch_bounds__(256) void fea_attn(
    const ushort* __restrict__ Qb, const ushort* __restrict__ Kb,
    const ushort* __restrict__ Vb, const float* __restrict__ OW,
    ushort* __restrict__ AObf) {
  const int bh = blockIdx.x >> 6;
  const int n  = blockIdx.x & 63;
  const int tid = threadIdx.x;
  const int t  = tid & 63;   // token within chunk (== lane)
  const int wv = tid >> 6;   // d-quarter
  __shared__ ushort Ks[80 * 64];
  __shared__ ushort Vs[80 * 64];
  __shared__ float ow[64];
  __shared__ float ps[4][18][64];
  const size_t base = (size_t)bh * T_TOT * 64;
  const int tok0 = n * 64;

  // ---- stage K/V: 640 16B-units, 256 threads, 3 sweeps ----
#pragma unroll
  for (int it = 0; it < 3; ++it) {
    const int u = it * 256 + tid;
    if (u < 640) {
      const int r = u >> 3, c16 = u & 7;
      const int tok = tok0 - 8 + r;
      uint4 kv = make_uint4(0, 0, 0, 0), vv = make_uint4(0, 0, 0, 0);
      if (tok >= 0 && tok < TFEA) {
        kv = *reinterpret_cast<const uint4*>(&Kb[base + (size_t)(NWTOK + tok) * 64 + c16 * 8]);
        vv = *reinterpret_cast<const uint4*>(&Vb[base + (size_t)(NWTOK + tok) * 64 + c16 * 8]);
      }
      const int sw = (c16 ^ (r & 7)) << 3;
      *reinterpret_cast<uint4*>(&Ks[r * 64 + sw]) = kv;
      *reinterpret_cast<uint4*>(&Vs[r * 64 + sw]) = vv;
    }
  }
  if (tid < 64) ow[tid] = OW[(bh * 64 + n) * 64 + tid];

  // ---- Q (this wave's 16 dims) -> registers ----
  float q[16];
  {
    const ushort* qr = &Qb[base + (size_t)(NWTOK + tok0 + t) * 64 + wv * 16];
#pragma unroll
    for (int h8 = 0; h8 < 2; ++h8) {
      const uint4 u4 = *reinterpret_cast<const uint4*>(&qr[h8 * 8]);
      unpack8(u4, &q[h8 * 8]);
    }
  }
  __syncthreads();

  // ---- partial scores (17 window + 1 summary) ----
  const int d0a = wv * 2, d0b = wv * 2 + 1;
#pragma unroll
  for (int w = 0; w < 17; ++w) {
    const int r = t + w, rx = r & 7;
    float f[16];
    const uint4 ua = *reinterpret_cast<const uint4*>(&Ks[r * 64 + ((d0a ^ rx) << 3)]);
    const uint4 ub = *reinterpret_cast<const uint4*>(&Ks[r * 64 + ((d0b ^ rx) << 3)]);
    unpack8(ua, f); unpack8(ub, f + 8);
    float acc = 0.f;
#pragma unroll
    for (int k = 0; k < 16; ++k) acc += q[k] * f[k];
    ps[wv][w][t] = acc;
  }
  {
    float acc = 0.f;
#pragma unroll
    for (int k = 0; k < 16; ++k) acc += q[k] * ow[wv * 16 + k];
    ps[wv][17][t] = acc;
  }
  __syncthreads();

  // ---- combine partials; softmaxes ----
  float s[17];
#pragma unroll
  for (int w = 0; w < 17; ++w)
    s[w] = ps[0][w][t] + ps[1][w][t] + ps[2][w][t] + ps[3][w][t];
  float s0 = ps[0][17][t] + ps[1][17][t] + ps[2][17][t] + ps[3][17][t];

  float m = s[0];
#pragma unroll
  for (int w = 1; w < 17; ++w) m = fmaxf(m, s[w]);
  float sum = 0.f;
#pragma unroll
  for (int w = 0; w < 17; ++w) { s[w] = __expf(s[w] - m); sum += s[w]; }
  const float inv = 1.f / sum;
#pragma unroll
  for (int w = 0; w < 17; ++w) s[w] *= inv;

  // chunk softmax of the summary score across the 64 tokens (t == lane)
  float mx = s0;
#pragma unroll
  for (int off = 32; off >= 1; off >>= 1) mx = fmaxf(mx, __shfl_xor(mx, off));
  const float e0 = __expf(s0 - mx);
  float es = e0;
#pragma unroll
  for (int off = 32; off >= 1; off >>= 1) es += __shfl_xor(es, off);
  const float w0 = e0 / es;

  // ---- PV for this wave's 16 dims; write packed bf16 ----
  const int bb = bh >> 3, h = bh & 7;
  ushort* orow = &AObf[((size_t)bb * T_TOT + NWTOK + tok0 + t) * 512 + h * 64 + wv * 16];
#pragma unroll
  for (int hb = 0; hb < 2; ++hb) {
    const int d0 = wv * 2 + hb;
    float o[8];
#pragma unroll
    for (int k = 0; k < 8; ++k) o[k] = w0 * ow[d0 * 8 + k];
#pragma unroll
    for (int w = 0; w < 17; ++w) {
      const int r = t + w, rx = r & 7;
      const uint4 u4 = *reinterpret_cast<const uint4*>(&Vs[r * 64 + ((d0 ^ rx) << 3)]);
      float f[8]; unpack8(u4, f);
#pragma unroll
      for (int k = 0; k < 8; ++k) o[k] += s[w] * f[k];
    }
    uint4 st;
    st.x = pk2(o[0], o[1]); st.y = pk2(o[2], o[3]);
    st.z = pk2(o[4], o[5]); st.w = pk2(o[6], o[7]);
    *reinterpret_cast<uint4*>(&orow[hb * 8]) = st;
  }
}

extern "C" void kernel_launch(void* const* d_in, const int* in_sizes, int n_in,
                              void* d_out, int out_size, void* d_ws, size_t ws_size,
                              hipStream_t stream) {
  const float* x    = (const float*)d_in[0];
  const float* Wqkv = (const float*)d_in[1];
  const float* bqkv = (const float*)d_in[2];
  const float* Wout = (const float*)d_in[3];
  const float* bout = (const float*)d_in[4];
  float* out = (float*)d_out;

  const size_t SZ = (size_t)16 * T_TOT * 64;  // 4,259,840 elements
  ushort* Qb = (ushort*)d_ws;
  ushort* Kb = Qb + SZ;
  ushort* Vb = Kb + SZ;
  float*  OW = (float*)(Vb + SZ);             // 65,536 f32 (16B-aligned)
  ushort* Xb    = (ushort*)(OW + 65536);
  ushort* WqkvT = Xb + SZ;
  ushort* WoutT = WqkvT + (size_t)1536 * 512;
  ushort* AObf  = WoutT + (size_t)512 * 512;

  conv_x<<<2080, 256, 0, stream>>>(x, Xb, (int)(SZ / 8));
  conv_wT<<<dim3(8, 24), 256, 0, stream>>>(Wqkv, WqkvT, 512, 1536);
  conv_wT<<<dim3(8, 8), 256, 0, stream>>>(Wout, WoutT, 512, 512);
  gemm_mfma<0><<<dim3(65, 12), 256, 0, stream>>>(Xb, WqkvT, bqkv, Qb, Kb, Vb);
  wtok_attn<<<1024, 64, 0, stream>>>(Qb, Kb, Vb, OW, AObf);
  fea_attn<<<1024, 256, 0, stream>>>(Qb, Kb, Vb, OW, AObf);
  gemm_mfma<1><<<dim3(65, 4), 256, 0, stream>>>(AObf, WoutT, bout, out, nullptr, nullptr);
}

// Round 10
// 142.886 us; speedup vs baseline: 3.0329x; 1.0025x over previous
//
#include <hip/hip_runtime.h>
#include <hip/hip_bf16.h>
#include <math.h>

#define T_TOT 4160
#define H_N   8
#define NWTOK 64
#define TFEA  4096

typedef __bf16 bf16x8 __attribute__((ext_vector_type(8)));
typedef float  f32x4  __attribute__((ext_vector_type(4)));

__device__ inline ushort f2b(float f) {
  __hip_bfloat16 h = __float2bfloat16(f);
  return *reinterpret_cast<ushort*>(&h);
}
__device__ inline float b2f(ushort u) {
  union { uint i; float v; } a;
  a.i = ((uint)u) << 16;
  return a.v;
}
__device__ inline uint pk2(float a, float b) {
  return (uint)f2b(a) | ((uint)f2b(b) << 16);
}
// unpack 8 bf16 (uint4) -> 8 f32
__device__ inline void unpack8(uint4 u, float* f) {
  union { uint i; float v; } a;
  a.i = u.x << 16;        f[0] = a.v;
  a.i = u.x & 0xffff0000u; f[1] = a.v;
  a.i = u.y << 16;        f[2] = a.v;
  a.i = u.y & 0xffff0000u; f[3] = a.v;
  a.i = u.z << 16;        f[4] = a.v;
  a.i = u.z & 0xffff0000u; f[5] = a.v;
  a.i = u.w << 16;        f[6] = a.v;
  a.i = u.w & 0xffff0000u; f[7] = a.v;
}

// ---------------------------------------------------------------------------
// conv_x: fp32 -> bf16, linear. 8 elems/thread, 16B stores.
// ---------------------------------------------------------------------------
__global__ __launch_bounds__(256) void conv_x(
    const float* __restrict__ X, ushort* __restrict__ Xb, int n8) {
  const int i = blockIdx.x * 256 + threadIdx.x;
  if (i >= n8) return;
  const float4 a = reinterpret_cast<const float4*>(X)[i * 2];
  const float4 b = reinterpret_cast<const float4*>(X)[i * 2 + 1];
  union { ushort u[8]; uint4 v; } r;
  r.u[0] = f2b(a.x); r.u[1] = f2b(a.y); r.u[2] = f2b(a.z); r.u[3] = f2b(a.w);
  r.u[4] = f2b(b.x); r.u[5] = f2b(b.y); r.u[6] = f2b(b.z); r.u[7] = f2b(b.w);
  reinterpret_cast<uint4*>(Xb)[i] = r.v;
}

// ---------------------------------------------------------------------------
// conv_w2: both weight transposes in one launch (z=0: Wqkv, z=1: Wout).
// W [512][C] fp32 -> WT [C][512] bf16, LDS 64x64 tiled.
// ---------------------------------------------------------------------------
__global__ __launch_bounds__(256) void conv_w2(
    const float* __restrict__ W0, ushort* __restrict__ WT0,
    const float* __restrict__ W1, ushort* __restrict__ WT1) {
  const int z = blockIdx.z;
  if (z == 1 && blockIdx.y >= 8) return;
  const float* __restrict__ W = z ? W1 : W0;
  ushort* __restrict__ WT = z ? WT1 : WT0;
  const int C = z ? 512 : 1536;
  __shared__ float tile[64][65];
  const int r0 = blockIdx.x * 64, c0 = blockIdx.y * 64;
  const int tid = threadIdx.x;
  const int rr = tid >> 4, c4 = (tid & 15) * 4;
#pragma unroll
  for (int q = 0; q < 4; ++q) {
    const int r = q * 16 + rr;
    const float4 v = *reinterpret_cast<const float4*>(&W[(size_t)(r0 + r) * C + c0 + c4]);
    tile[r][c4] = v.x; tile[r][c4 + 1] = v.y; tile[r][c4 + 2] = v.z; tile[r][c4 + 3] = v.w;
  }
  __syncthreads();
#pragma unroll
  for (int q = 0; q < 4; ++q) {
    const int cr = q * 16 + rr;
    ushort4 o;
    o.x = f2b(tile[c4][cr]);
    o.y = f2b(tile[c4 + 1][cr]);
    o.z = f2b(tile[c4 + 2][cr]);
    o.w = f2b(tile[c4 + 3][cr]);
    *reinterpret_cast<ushort4*>(&WT[(size_t)(c0 + cr) * 512 + r0 + c4]) = o;
  }
}

// ---------------------------------------------------------------------------
// gemm_mfma: C[M x N] = A[M x 512] * BT[N x 512]^T, bf16 in, f32 accum.
// 128x128 tile, BK=64, 4 waves, 16x16x32 bf16 MFMA, global_load_lds staging,
// T2 XOR swizzle (linear LDS dest + inverse-swz global source + swz read).
// MODE 0: qkv epilogue -> bf16 Q/K/V in head layout (Q scaled).
// MODE 1: out epilogue -> f32 O0[m*512+n].
// ---------------------------------------------------------------------------
template<int MODE>
__global__ __launch_bounds__(256) void gemm_mfma(
    const ushort* __restrict__ A, const ushort* __restrict__ BT,
    const float* __restrict__ bias, void* __restrict__ O0v,
    void* __restrict__ O1v, void* __restrict__ O2v) {
  __shared__ ushort sA[128 * 64];
  __shared__ ushort sB[128 * 64];
  const int tid = threadIdx.x;
  const int lane = tid & 63, wave = tid >> 6;
  const int m0 = blockIdx.x * 128, n0 = blockIdx.y * 128;
  const int wm = wave >> 1, wn = wave & 1;

  f32x4 acc[4][4] = {};

  auto stage = [&](int kt) {
    const ushort* Ag = A + (size_t)m0 * 512 + kt * 64;
    const ushort* Bg = BT + (size_t)n0 * 512 + kt * 64;
#pragma unroll
    for (int r = 0; r < 4; ++r) {
      const int rowbase = r * 32 + wave * 8;
      const int row = rowbase + (lane >> 3);
      const int c = lane & 7;
      const int cc = c ^ (row & 7);
      __builtin_amdgcn_global_load_lds(
          (const __attribute__((address_space(1))) void*)(Ag + (size_t)row * 512 + cc * 8),
          (__attribute__((address_space(3))) void*)(sA + rowbase * 64), 16, 0, 0);
      __builtin_amdgcn_global_load_lds(
          (const __attribute__((address_space(1))) void*)(Bg + (size_t)row * 512 + cc * 8),
          (__attribute__((address_space(3))) void*)(sB + rowbase * 64), 16, 0, 0);
    }
  };

  stage(0);
  for (int kt = 0; kt < 8; ++kt) {
    __syncthreads();
#pragma unroll
    for (int ks = 0; ks < 2; ++ks) {
      bf16x8 af[4], bfr[4];
      const int cc = ks * 4 + (lane >> 4);
      const int rA = wm * 64 + (lane & 15);
      const int rB = wn * 64 + (lane & 15);
#pragma unroll
      for (int i = 0; i < 4; ++i) {
        const int ra = rA + i * 16;
        af[i] = *reinterpret_cast<const bf16x8*>(&sA[ra * 64 + ((cc ^ (ra & 7)) << 3)]);
        const int rb = rB + i * 16;
        bfr[i] = *reinterpret_cast<const bf16x8*>(&sB[rb * 64 + ((cc ^ (rb & 7)) << 3)]);
      }
#pragma unroll
      for (int i = 0; i < 4; ++i)
#pragma unroll
        for (int j = 0; j < 4; ++j)
          acc[i][j] = __builtin_amdgcn_mfma_f32_16x16x32_bf16(af[i], bfr[j], acc[i][j], 0, 0, 0);
    }
    __syncthreads();
    if (kt < 7) stage(kt + 1);
  }

#pragma unroll
  for (int i = 0; i < 4; ++i) {
#pragma unroll
    for (int j = 0; j < 4; ++j) {
      const f32x4 a = acc[i][j];
      const int n = n0 + wn * 64 + j * 16 + (lane & 15);
      const float bv = bias[n];
#pragma unroll
      for (int r = 0; r < 4; ++r) {
        const int m = m0 + wm * 64 + i * 16 + ((lane >> 4) << 2) + r;
        const float v = a[r] + bv;
        if (MODE == 0) {
          const int bb = m / T_TOT, t = m - bb * T_TOT;
          const int which = n >> 9, e = n & 511;
          const int h = e >> 6, d = e & 63;
          const size_t idx = ((size_t)(bb * H_N + h) * T_TOT + t) * 64 + d;
          if (which == 0)      ((ushort*)O0v)[idx] = f2b(v * 0.125f);
          else if (which == 1) ((ushort*)O1v)[idx] = f2b(v);
          else                 ((ushort*)O2v)[idx] = f2b(v);
        } else {
          ((float*)O0v)[(size_t)m * 512 + n] = v;
        }
      }
    }
  }
}

// ---------------------------------------------------------------------------
// fused_attn: wtok + feature local attention in one kernel.
// Block (bh, n): stages the 80-row K/V window; the 64 chunk tokens
// [n*64, n*64+64) double as the wtok candidates for wtok token n, so
// Phase A computes out_wtok in-block (redundant per wave; lane l = chunk
// candidate l+1 from LDS, candidate 0 from a broadcast Kw/Vw row), writes
// ow to LDS + the token-n output row. Phase B = round-6 fea_attn.
// LDS 39.7 KB -> 4 blocks/CU x 4 waves. Zero-pad window semantics kept.
// ---------------------------------------------------------------------------
__global__ __launch_bounds__(256) void fused_attn(
    const ushort* __restrict__ Qb, const ushort* __restrict__ Kb,
    const ushort* __restrict__ Vb, ushort* __restrict__ AObf) {
  const int bh = blockIdx.x >> 6;
  const int n  = blockIdx.x & 63;
  const int tid = threadIdx.x;
  const int t  = tid & 63;   // token within chunk (== lane) / wtok candidate-1
  const int wv = tid >> 6;   // d-quarter
  __shared__ ushort Ks[80 * 64];
  __shared__ ushort Vs[80 * 64];
  __shared__ ushort kwr[64];
  __shared__ ushort vwr[64];
  __shared__ float qw[64];
  __shared__ float ow[64];
  __shared__ float ps[4][18][64];
  const size_t base = (size_t)bh * T_TOT * 64;
  const int tok0 = n * 64;

  // ---- stage K/V window: 640 16B-units, 3 sweeps ----
#pragma unroll
  for (int it = 0; it < 3; ++it) {
    const int u = it * 256 + tid;
    if (u < 640) {
      const int r = u >> 3, c16 = u & 7;
      const int tok = tok0 - 8 + r;
      uint4 kv = make_uint4(0, 0, 0, 0), vv = make_uint4(0, 0, 0, 0);
      if (tok >= 0 && tok < TFEA) {
        kv = *reinterpret_cast<const uint4*>(&Kb[base + (size_t)(NWTOK + tok) * 64 + c16 * 8]);
        vv = *reinterpret_cast<const uint4*>(&Vb[base + (size_t)(NWTOK + tok) * 64 + c16 * 8]);
      }
      const int sw = (c16 ^ (r & 7)) << 3;
      *reinterpret_cast<uint4*>(&Ks[r * 64 + sw]) = kv;
      *reinterpret_cast<uint4*>(&Vs[r * 64 + sw]) = vv;
    }
  }
  // ---- wtok token rows + wtok query ----
  if (tid < 8)
    *reinterpret_cast<uint4*>(&kwr[tid * 8]) =
        *reinterpret_cast<const uint4*>(&Kb[base + n * 64 + tid * 8]);
  else if (tid < 16)
    *reinterpret_cast<uint4*>(&vwr[(tid - 8) * 8]) =
        *reinterpret_cast<const uint4*>(&Vb[base + n * 64 + (tid - 8) * 8]);
  else if (tid < 32) {
    const int j = tid - 16;
    const ushort4 u = *reinterpret_cast<const ushort4*>(&Qb[base + n * 64 + j * 4]);
    qw[j * 4 + 0] = b2f(u.x); qw[j * 4 + 1] = b2f(u.y);
    qw[j * 4 + 2] = b2f(u.z); qw[j * 4 + 3] = b2f(u.w);
  }

  // ---- Q (this wave's 16 dims) -> registers ----
  float q[16];
  {
    const ushort* qr = &Qb[base + (size_t)(NWTOK + tok0 + t) * 64 + wv * 16];
#pragma unroll
    for (int h8 = 0; h8 < 2; ++h8) {
      const uint4 u4 = *reinterpret_cast<const uint4*>(&qr[h8 * 8]);
      unpack8(u4, &q[h8 * 8]);
    }
  }
  __syncthreads();

  // ================= Phase A: wtok attention (redundant per wave) ========
  float aw_l, aw0;
  {
    // candidate t+1 = chunk token t -> staged row t+8; candidate 0 = kwr.
    const int row = t + 8, r7 = row & 7;
    float acc = 0.f, acc0 = 0.f;
#pragma unroll
    for (int g = 0; g < 8; ++g) {
      float f[8], f0[8];
      const uint4 u  = *reinterpret_cast<const uint4*>(&Ks[row * 64 + ((g ^ r7) << 3)]);
      const uint4 u0 = *reinterpret_cast<const uint4*>(&kwr[g * 8]);  // broadcast
      unpack8(u, f); unpack8(u0, f0);
#pragma unroll
      for (int k = 0; k < 8; ++k) {
        const float qv = qw[g * 8 + k];  // broadcast
        acc  += qv * f[k];
        acc0 += qv * f0[k];
      }
    }
    float mx = fmaxf(acc, acc0);
#pragma unroll
    for (int off = 32; off >= 1; off >>= 1) mx = fmaxf(mx, __shfl_xor(mx, off));
    const float e = __expf(acc - mx), e0 = __expf(acc0 - mx);
    float sum = e;
#pragma unroll
    for (int off = 32; off >= 1; off >>= 1) sum += __shfl_xor(sum, off);
    sum += e0;                 // candidate 0 counted once (uniform)
    aw_l = e / sum;
    aw0  = e0 / sum;
  }
  {
    // ow partials for this wave's 16 dims; butterfly-sum over 64 candidates.
    float pv[16];
    const int row = t + 8, r7 = row & 7;
    const float a0 = (t == 0) ? aw0 : 0.f;   // add candidate-0 term once
#pragma unroll
    for (int hb = 0; hb < 2; ++hb) {
      const int g = wv * 2 + hb;
      float f[8], f0[8];
      const uint4 u  = *reinterpret_cast<const uint4*>(&Vs[row * 64 + ((g ^ r7) << 3)]);
      const uint4 u0 = *reinterpret_cast<const uint4*>(&vwr[g * 8]);  // broadcast
      unpack8(u, f); unpack8(u0, f0);
#pragma unroll
      for (int k = 0; k < 8; ++k) pv[hb * 8 + k] = aw_l * f[k] + a0 * f0[k];
    }
#pragma unroll
    for (int off = 1; off < 64; off <<= 1)
#pragma unroll
      for (int k = 0; k < 16; ++k) pv[k] += __shfl_xor(pv[k], off);
    if (t == 0) {
#pragma unroll
      for (int k = 0; k < 16; ++k) ow[wv * 16 + k] = pv[k];
      uint4 s1, s2;
      s1.x = pk2(pv[0], pv[1]);   s1.y = pk2(pv[2], pv[3]);
      s1.z = pk2(pv[4], pv[5]);   s1.w = pk2(pv[6], pv[7]);
      s2.x = pk2(pv[8], pv[9]);   s2.y = pk2(pv[10], pv[11]);
      s2.z = pk2(pv[12], pv[13]); s2.w = pk2(pv[14], pv[15]);
      ushort* orow = &AObf[((size_t)(bh >> 3) * T_TOT + n) * 512 + (bh & 7) * 64 + wv * 16];
      *reinterpret_cast<uint4*>(&orow[0]) = s1;
      *reinterpret_cast<uint4*>(&orow[8]) = s2;
    }
  }
  __syncthreads();   // ow ready

  // ================= Phase B: feature local attention =====================
  const int d0a = wv * 2, d0b = wv * 2 + 1;
#pragma unroll
  for (int w = 0; w < 17; ++w) {
    const int r = t + w, rx = r & 7;
    float f[16];
    const uint4 ua = *reinterpret_cast<const uint4*>(&Ks[r * 64 + ((d0a ^ rx) << 3)]);
    const uint4 ub = *reinterpret_cast<const uint4*>(&Ks[r * 64 + ((d0b ^ rx) << 3)]);
    unpack8(ua, f); unpack8(ub, f + 8);
    float acc = 0.f;
#pragma unroll
    for (int k = 0; k < 16; ++k) acc += q[k] * f[k];
    ps[wv][w][t] = acc;
  }
  {
    float acc = 0.f;
#pragma unroll
    for (int k = 0; k < 16; ++k) acc += q[k] * ow[wv * 16 + k];
    ps[wv][17][t] = acc;
  }
  __syncthreads();

  float s[17];
#pragma unroll
  for (int w = 0; w < 17; ++w)
    s[w] = ps[0][w][t] + ps[1][w][t] + ps[2][w][t] + ps[3][w][t];
  float s0 = ps[0][17][t] + ps[1][17][t] + ps[2][17][t] + ps[3][17][t];

  float m = s[0];
#pragma unroll
  for (int w = 1; w < 17; ++w) m = fmaxf(m, s[w]);
  float sum = 0.f;
#pragma unroll
  for (int w = 0; w < 17; ++w) { s[w] = __expf(s[w] - m); sum += s[w]; }
  const float inv = 1.f / sum;
#pragma unroll
  for (int w = 0; w < 17; ++w) s[w] *= inv;

  float mx = s0;
#pragma unroll
  for (int off = 32; off >= 1; off >>= 1) mx = fmaxf(mx, __shfl_xor(mx, off));
  const float e0 = __expf(s0 - mx);
  float es = e0;
#pragma unroll
  for (int off = 32; off >= 1; off >>= 1) es += __shfl_xor(es, off);
  const float w0 = e0 / es;

  const int bb = bh >> 3, h = bh & 7;
  ushort* orow = &AObf[((size_t)bb * T_TOT + NWTOK + tok0 + t) * 512 + h * 64 + wv * 16];
#pragma unroll
  for (int hb = 0; hb < 2; ++hb) {
    const int d0 = wv * 2 + hb;
    float o[8];
#pragma unroll
    for (int k = 0; k < 8; ++k) o[k] = w0 * ow[d0 * 8 + k];
#pragma unroll
    for (int w = 0; w < 17; ++w) {
      const int r = t + w, rx = r & 7;
      const uint4 u4 = *reinterpret_cast<const uint4*>(&Vs[r * 64 + ((d0 ^ rx) << 3)]);
      float f[8]; unpack8(u4, f);
#pragma unroll
      for (int k = 0; k < 8; ++k) o[k] += s[w] * f[k];
    }
    uint4 st;
    st.x = pk2(o[0], o[1]); st.y = pk2(o[2], o[3]);
    st.z = pk2(o[4], o[5]); st.w = pk2(o[6], o[7]);
    *reinterpret_cast<uint4*>(&orow[hb * 8]) = st;
  }
}

extern "C" void kernel_launch(void* const* d_in, const int* in_sizes, int n_in,
                              void* d_out, int out_size, void* d_ws, size_t ws_size,
                              hipStream_t stream) {
  const float* x    = (const float*)d_in[0];
  const float* Wqkv = (const float*)d_in[1];
  const float* bqkv = (const float*)d_in[2];
  const float* Wout = (const float*)d_in[3];
  const float* bout = (const float*)d_in[4];
  float* out = (float*)d_out;

  const size_t SZ = (size_t)16 * T_TOT * 64;  // 4,259,840 elements
  ushort* Qb = (ushort*)d_ws;
  ushort* Kb = Qb + SZ;
  ushort* Vb = Kb + SZ;
  ushort* Xb    = Vb + SZ;
  ushort* WqkvT = Xb + SZ;
  ushort* WoutT = WqkvT + (size_t)1536 * 512;
  ushort* AObf  = WoutT + (size_t)512 * 512;

  conv_x<<<2080, 256, 0, stream>>>(x, Xb, (int)(SZ / 8));
  conv_w2<<<dim3(8, 24, 2), 256, 0, stream>>>(Wqkv, WqkvT, Wout, WoutT);
  gemm_mfma<0><<<dim3(65, 12), 256, 0, stream>>>(Xb, WqkvT, bqkv, Qb, Kb, Vb);
  fused_attn<<<1024, 256, 0, stream>>>(Qb, Kb, Vb, AObf);
  gemm_mfma<1><<<dim3(65, 4), 256, 0, stream>>>(AObf, WoutT, bout, out, nullptr, nullptr);
}

// Round 11
// 142.644 us; speedup vs baseline: 3.0381x; 1.0017x over previous
//
#include <hip/hip_runtime.h>
#include <hip/hip_bf16.h>
#include <math.h>

#define T_TOT 4160
#define H_N   8
#define NWTOK 64
#define TFEA  4096

typedef __bf16 bf16x8 __attribute__((ext_vector_type(8)));
typedef float  f32x4  __attribute__((ext_vector_type(4)));

__device__ inline ushort f2b(float f) {
  __hip_bfloat16 h = __float2bfloat16(f);
  return *reinterpret_cast<ushort*>(&h);
}
__device__ inline float b2f(ushort u) {
  union { uint i; float v; } a;
  a.i = ((uint)u) << 16;
  return a.v;
}
__device__ inline uint pk2(float a, float b) {
  return (uint)f2b(a) | ((uint)f2b(b) << 16);
}
// unpack 8 bf16 (uint4) -> 8 f32
__device__ inline void unpack8(uint4 u, float* f) {
  union { uint i; float v; } a;
  a.i = u.x << 16;        f[0] = a.v;
  a.i = u.x & 0xffff0000u; f[1] = a.v;
  a.i = u.y << 16;        f[2] = a.v;
  a.i = u.y & 0xffff0000u; f[3] = a.v;
  a.i = u.z << 16;        f[4] = a.v;
  a.i = u.z & 0xffff0000u; f[5] = a.v;
  a.i = u.w << 16;        f[6] = a.v;
  a.i = u.w & 0xffff0000u; f[7] = a.v;
}

// ---------------------------------------------------------------------------
// conv_x: fp32 -> bf16, linear. 8 elems/thread, 16B stores.
// ---------------------------------------------------------------------------
__global__ __launch_bounds__(256) void conv_x(
    const float* __restrict__ X, ushort* __restrict__ Xb, int n8) {
  const int i = blockIdx.x * 256 + threadIdx.x;
  if (i >= n8) return;
  const float4 a = reinterpret_cast<const float4*>(X)[i * 2];
  const float4 b = reinterpret_cast<const float4*>(X)[i * 2 + 1];
  union { ushort u[8]; uint4 v; } r;
  r.u[0] = f2b(a.x); r.u[1] = f2b(a.y); r.u[2] = f2b(a.z); r.u[3] = f2b(a.w);
  r.u[4] = f2b(b.x); r.u[5] = f2b(b.y); r.u[6] = f2b(b.z); r.u[7] = f2b(b.w);
  reinterpret_cast<uint4*>(Xb)[i] = r.v;
}

// ---------------------------------------------------------------------------
// conv_w2: both weight transposes in one launch (z=0: Wqkv, z=1: Wout).
// ---------------------------------------------------------------------------
__global__ __launch_bounds__(256) void conv_w2(
    const float* __restrict__ W0, ushort* __restrict__ WT0,
    const float* __restrict__ W1, ushort* __restrict__ WT1) {
  const int z = blockIdx.z;
  if (z == 1 && blockIdx.y >= 8) return;
  const float* __restrict__ W = z ? W1 : W0;
  ushort* __restrict__ WT = z ? WT1 : WT0;
  const int C = z ? 512 : 1536;
  __shared__ float tile[64][65];
  const int r0 = blockIdx.x * 64, c0 = blockIdx.y * 64;
  const int tid = threadIdx.x;
  const int rr = tid >> 4, c4 = (tid & 15) * 4;
#pragma unroll
  for (int q = 0; q < 4; ++q) {
    const int r = q * 16 + rr;
    const float4 v = *reinterpret_cast<const float4*>(&W[(size_t)(r0 + r) * C + c0 + c4]);
    tile[r][c4] = v.x; tile[r][c4 + 1] = v.y; tile[r][c4 + 2] = v.z; tile[r][c4 + 3] = v.w;
  }
  __syncthreads();
#pragma unroll
  for (int q = 0; q < 4; ++q) {
    const int cr = q * 16 + rr;
    ushort4 o;
    o.x = f2b(tile[c4][cr]);
    o.y = f2b(tile[c4 + 1][cr]);
    o.z = f2b(tile[c4 + 2][cr]);
    o.w = f2b(tile[c4 + 3][cr]);
    *reinterpret_cast<ushort4*>(&WT[(size_t)(c0 + cr) * 512 + r0 + c4]) = o;
  }
}

// ---------------------------------------------------------------------------
// gemm_mfma: C[M x N] = A[M x 512] * BT[N x 512]^T, bf16 in, f32 accum.
// MODE 0: BN=128 (grid 65x12), qkv epilogue -> bf16 Q/K/V head layout.
// MODE 1: BN=64  (grid 65x8 = 520 blocks = 2/CU, fixes 1-block/CU occupancy),
//         out epilogue -> f32 O0[m*512+n].
// ---------------------------------------------------------------------------
template<int MODE>
__global__ __launch_bounds__(256) void gemm_mfma(
    const ushort* __restrict__ A, const ushort* __restrict__ BT,
    const float* __restrict__ bias, void* __restrict__ O0v,
    void* __restrict__ O1v, void* __restrict__ O2v) {
  constexpr int BN = (MODE == 0) ? 128 : 64;
  constexpr int WN = BN / 2;          // per-wave n extent
  constexpr int NJ = WN / 16;         // n fragments per wave
  __shared__ ushort sA[128 * 64];
  __shared__ ushort sB[BN * 64];
  const int tid = threadIdx.x;
  const int lane = tid & 63, wave = tid >> 6;
  const int m0 = blockIdx.x * 128, n0 = blockIdx.y * BN;
  const int wm = wave >> 1, wn = wave & 1;

  f32x4 acc[4][NJ] = {};

  auto stage = [&](int kt) {
    const ushort* Ag = A + (size_t)m0 * 512 + kt * 64;
    const ushort* Bg = BT + (size_t)n0 * 512 + kt * 64;
#pragma unroll
    for (int r = 0; r < 4; ++r) {
      const int rowbase = r * 32 + wave * 8;
      const int row = rowbase + (lane >> 3);
      const int c = lane & 7;
      const int cc = c ^ (row & 7);
      __builtin_amdgcn_global_load_lds(
          (const __attribute__((address_space(1))) void*)(Ag + (size_t)row * 512 + cc * 8),
          (__attribute__((address_space(3))) void*)(sA + rowbase * 64), 16, 0, 0);
      if (r < BN / 32)
        __builtin_amdgcn_global_load_lds(
            (const __attribute__((address_space(1))) void*)(Bg + (size_t)row * 512 + cc * 8),
            (__attribute__((address_space(3))) void*)(sB + rowbase * 64), 16, 0, 0);
    }
  };

  stage(0);
  for (int kt = 0; kt < 8; ++kt) {
    __syncthreads();
#pragma unroll
    for (int ks = 0; ks < 2; ++ks) {
      bf16x8 af[4], bfr[NJ];
      const int cc = ks * 4 + (lane >> 4);
      const int rA = wm * 64 + (lane & 15);
#pragma unroll
      for (int i = 0; i < 4; ++i) {
        const int ra = rA + i * 16;
        af[i] = *reinterpret_cast<const bf16x8*>(&sA[ra * 64 + ((cc ^ (ra & 7)) << 3)]);
      }
#pragma unroll
      for (int j = 0; j < NJ; ++j) {
        const int rb = wn * WN + j * 16 + (lane & 15);
        bfr[j] = *reinterpret_cast<const bf16x8*>(&sB[rb * 64 + ((cc ^ (rb & 7)) << 3)]);
      }
#pragma unroll
      for (int i = 0; i < 4; ++i)
#pragma unroll
        for (int j = 0; j < NJ; ++j)
          acc[i][j] = __builtin_amdgcn_mfma_f32_16x16x32_bf16(af[i], bfr[j], acc[i][j], 0, 0, 0);
    }
    __syncthreads();
    if (kt < 7) stage(kt + 1);
  }

#pragma unroll
  for (int i = 0; i < 4; ++i) {
#pragma unroll
    for (int j = 0; j < NJ; ++j) {
      const f32x4 a = acc[i][j];
      const int n = n0 + wn * WN + j * 16 + (lane & 15);
      const float bv = bias[n];
#pragma unroll
      for (int r = 0; r < 4; ++r) {
        const int m = m0 + wm * 64 + i * 16 + ((lane >> 4) << 2) + r;
        const float v = a[r] + bv;
        if (MODE == 0) {
          const int bb = m / T_TOT, t = m - bb * T_TOT;
          const int which = n >> 9, e = n & 511;
          const int h = e >> 6, d = e & 63;
          const size_t idx = ((size_t)(bb * H_N + h) * T_TOT + t) * 64 + d;
          if (which == 0)      ((ushort*)O0v)[idx] = f2b(v * 0.125f);
          else if (which == 1) ((ushort*)O1v)[idx] = f2b(v);
          else                 ((ushort*)O2v)[idx] = f2b(v);
        } else {
          ((float*)O0v)[(size_t)m * 512 + n] = v;
        }
      }
    }
  }
}

// ---------------------------------------------------------------------------
// fused_attn v2: wtok + feature local attention, MFMA scores.
// K and V time-share one 80x64 bf16 LDS buffer; S = Q·K^T via MFMA into
// S[64][80] f32 LDS; per-token softmax reads its 17-band; V is reg-staged
// under the softmax (T14) and overwrites KV after the K-reads barrier.
// ---------------------------------------------------------------------------
__global__ __launch_bounds__(256) void fused_attn(
    const ushort* __restrict__ Qb, const ushort* __restrict__ Kb,
    const ushort* __restrict__ Vb, ushort* __restrict__ AObf) {
  const int bh = blockIdx.x >> 6;
  const int n  = blockIdx.x & 63;
  const int tid = threadIdx.x;
  const int t  = tid & 63;   // token within chunk (== lane)
  const int wv = tid >> 6;   // wave index
  __shared__ ushort KV[80 * 64];
  __shared__ float  S[64 * 80];
  __shared__ ushort kwr[64];
  __shared__ ushort vwr[64];
  __shared__ float qw[64];
  __shared__ float ow[64];
  __shared__ float ps0[4][64];
  const size_t base = (size_t)bh * T_TOT * 64;
  const int tok0 = n * 64;

  // ---- stage K window into KV (640 16B-units, swizzled dest) ----
#pragma unroll
  for (int it = 0; it < 3; ++it) {
    const int u = it * 256 + tid;
    if (u < 640) {
      const int r = u >> 3, c16 = u & 7;
      const int tok = tok0 - 8 + r;
      uint4 kv = make_uint4(0, 0, 0, 0);
      if (tok >= 0 && tok < TFEA)
        kv = *reinterpret_cast<const uint4*>(&Kb[base + (size_t)(NWTOK + tok) * 64 + c16 * 8]);
      *reinterpret_cast<uint4*>(&KV[r * 64 + ((c16 ^ (r & 7)) << 3)]) = kv;
    }
  }
  if (tid < 8)
    *reinterpret_cast<uint4*>(&kwr[tid * 8]) =
        *reinterpret_cast<const uint4*>(&Kb[base + n * 64 + tid * 8]);
  else if (tid < 16)
    *reinterpret_cast<uint4*>(&vwr[(tid - 8) * 8]) =
        *reinterpret_cast<const uint4*>(&Vb[base + n * 64 + (tid - 8) * 8]);
  else if (tid < 32) {
    const int j = tid - 16;
    const ushort4 u = *reinterpret_cast<const ushort4*>(&Qb[base + n * 64 + j * 4]);
    qw[j * 4 + 0] = b2f(u.x); qw[j * 4 + 1] = b2f(u.y);
    qw[j * 4 + 2] = b2f(u.z); qw[j * 4 + 3] = b2f(u.w);
  }
  __syncthreads();   // b1: K staged

  // ===== Phase A score part (reads KV = K) =====
  float aw_l, aw0;
  {
    const int row = t + 8, r7 = row & 7;
    float acc = 0.f, acc0 = 0.f;
#pragma unroll
    for (int g = 0; g < 8; ++g) {
      float f[8], f0[8];
      const uint4 u  = *reinterpret_cast<const uint4*>(&KV[row * 64 + ((g ^ r7) << 3)]);
      const uint4 u0 = *reinterpret_cast<const uint4*>(&kwr[g * 8]);
      unpack8(u, f); unpack8(u0, f0);
#pragma unroll
      for (int k = 0; k < 8; ++k) {
        const float qv = qw[g * 8 + k];
        acc  += qv * f[k];
        acc0 += qv * f0[k];
      }
    }
    float mx = fmaxf(acc, acc0);
#pragma unroll
    for (int off = 32; off >= 1; off >>= 1) mx = fmaxf(mx, __shfl_xor(mx, off));
    const float e = __expf(acc - mx), e0 = __expf(acc0 - mx);
    float sum = e;
#pragma unroll
    for (int off = 32; off >= 1; off >>= 1) sum += __shfl_xor(sum, off);
    sum += e0;
    aw_l = e / sum;
    aw0  = e0 / sum;
  }

  // ===== S = Q·K^T via MFMA (wave strip = tokens [wv*16, wv*16+16)) =====
  {
    f32x4 accs[5] = {};
#pragma unroll
    for (int kt = 0; kt < 2; ++kt) {
      const bf16x8 a = *reinterpret_cast<const bf16x8*>(
          &Qb[base + (size_t)(NWTOK + tok0 + wv * 16 + (t & 15)) * 64 +
              kt * 32 + ((t >> 4) << 3)]);
#pragma unroll
      for (int j = 0; j < 5; ++j) {
        const int key = j * 16 + (t & 15);
        const int koff8 = kt * 4 + (t >> 4);
        const bf16x8 b = *reinterpret_cast<const bf16x8*>(
            &KV[key * 64 + ((koff8 ^ (key & 7)) << 3)]);
        accs[j] = __builtin_amdgcn_mfma_f32_16x16x32_bf16(a, b, accs[j], 0, 0, 0);
      }
    }
#pragma unroll
    for (int j = 0; j < 5; ++j)
#pragma unroll
      for (int r = 0; r < 4; ++r)
        S[(wv * 16 + ((t >> 4) << 2) + r) * 80 + j * 16 + (t & 15)] = accs[j][r];
  }
  __syncthreads();   // b2: K reads done, S visible

  // ---- issue V loads into registers (hide under softmax) ----
  uint4 vreg0 = make_uint4(0, 0, 0, 0), vreg1 = vreg0, vreg2 = vreg0;
  {
    const int u0 = tid, u1 = 256 + tid, u2 = 512 + tid;
    { const int r = u0 >> 3, c16 = u0 & 7, tok = tok0 - 8 + r;
      if (tok >= 0 && tok < TFEA)
        vreg0 = *reinterpret_cast<const uint4*>(&Vb[base + (size_t)(NWTOK + tok) * 64 + c16 * 8]); }
    { const int r = u1 >> 3, c16 = u1 & 7, tok = tok0 - 8 + r;
      if (tok >= 0 && tok < TFEA)
        vreg1 = *reinterpret_cast<const uint4*>(&Vb[base + (size_t)(NWTOK + tok) * 64 + c16 * 8]); }
    if (u2 < 640) {
      const int r = u2 >> 3, c16 = u2 & 7, tok = tok0 - 8 + r;
      if (tok >= 0 && tok < TFEA)
        vreg2 = *reinterpret_cast<const uint4*>(&Vb[base + (size_t)(NWTOK + tok) * 64 + c16 * 8]);
    }
  }

  // ---- window softmax from S band ----
  float s[17];
  {
    const float* Srow = &S[t * 80];
    float m = -1e30f;
#pragma unroll
    for (int w = 0; w < 17; ++w) { s[w] = Srow[t + w]; m = fmaxf(m, s[w]); }
    float sum = 0.f;
#pragma unroll
    for (int w = 0; w < 17; ++w) { s[w] = __expf(s[w] - m); sum += s[w]; }
    const float inv = 1.f / sum;
#pragma unroll
    for (int w = 0; w < 17; ++w) s[w] *= inv;
  }

  // ---- write V into KV (swizzled) ----
  {
    const int u0 = tid, u1 = 256 + tid, u2 = 512 + tid;
    { const int r = u0 >> 3, c16 = u0 & 7;
      *reinterpret_cast<uint4*>(&KV[r * 64 + ((c16 ^ (r & 7)) << 3)]) = vreg0; }
    { const int r = u1 >> 3, c16 = u1 & 7;
      *reinterpret_cast<uint4*>(&KV[r * 64 + ((c16 ^ (r & 7)) << 3)]) = vreg1; }
    if (u2 < 640) {
      const int r = u2 >> 3, c16 = u2 & 7;
      *reinterpret_cast<uint4*>(&KV[r * 64 + ((c16 ^ (r & 7)) << 3)]) = vreg2;
    }
  }
  __syncthreads();   // b3: V ready

  // ===== Phase A V-part: ow = wtok PV (reads KV = V) =====
  {
    float pv[16];
    const int row = t + 8, r7 = row & 7;
    const float a0 = (t == 0) ? aw0 : 0.f;
#pragma unroll
    for (int hb = 0; hb < 2; ++hb) {
      const int g = wv * 2 + hb;
      float f[8], f0[8];
      const uint4 u  = *reinterpret_cast<const uint4*>(&KV[row * 64 + ((g ^ r7) << 3)]);
      const uint4 u0 = *reinterpret_cast<const uint4*>(&vwr[g * 8]);
      unpack8(u, f); unpack8(u0, f0);
#pragma unroll
      for (int k = 0; k < 8; ++k) pv[hb * 8 + k] = aw_l * f[k] + a0 * f0[k];
    }
#pragma unroll
    for (int off = 1; off < 64; off <<= 1)
#pragma unroll
      for (int k = 0; k < 16; ++k) pv[k] += __shfl_xor(pv[k], off);
    if (t == 0) {
#pragma unroll
      for (int k = 0; k < 16; ++k) ow[wv * 16 + k] = pv[k];
      uint4 s1, s2;
      s1.x = pk2(pv[0], pv[1]);   s1.y = pk2(pv[2], pv[3]);
      s1.z = pk2(pv[4], pv[5]);   s1.w = pk2(pv[6], pv[7]);
      s2.x = pk2(pv[8], pv[9]);   s2.y = pk2(pv[10], pv[11]);
      s2.z = pk2(pv[12], pv[13]); s2.w = pk2(pv[14], pv[15]);
      ushort* orow = &AObf[((size_t)(bh >> 3) * T_TOT + n) * 512 + (bh & 7) * 64 + wv * 16];
      *reinterpret_cast<uint4*>(&orow[0]) = s1;
      *reinterpret_cast<uint4*>(&orow[8]) = s2;
    }
  }
  __syncthreads();   // b4: ow ready

  // ---- summary score partial for this wave's d-quarter ----
  {
    float q[16];
    const ushort* qr = &Qb[base + (size_t)(NWTOK + tok0 + t) * 64 + wv * 16];
#pragma unroll
    for (int h8 = 0; h8 < 2; ++h8) {
      const uint4 u4 = *reinterpret_cast<const uint4*>(&qr[h8 * 8]);
      unpack8(u4, &q[h8 * 8]);
    }
    float acc = 0.f;
#pragma unroll
    for (int k = 0; k < 16; ++k) acc += q[k] * ow[wv * 16 + k];
    ps0[wv][t] = acc;
  }
  __syncthreads();   // b5: ps0 ready

  float s0 = ps0[0][t] + ps0[1][t] + ps0[2][t] + ps0[3][t];
  float mx = s0;
#pragma unroll
  for (int off = 32; off >= 1; off >>= 1) mx = fmaxf(mx, __shfl_xor(mx, off));
  const float e0 = __expf(s0 - mx);
  float es = e0;
#pragma unroll
  for (int off = 32; off >= 1; off >>= 1) es += __shfl_xor(es, off);
  const float w0 = e0 / es;

  // ===== PV for this wave's 16 dims (reads KV = V) =====
  const int bb = bh >> 3, h = bh & 7;
  ushort* orow = &AObf[((size_t)bb * T_TOT + NWTOK + tok0 + t) * 512 + h * 64 + wv * 16];
#pragma unroll
  for (int hb = 0; hb < 2; ++hb) {
    const int d0 = wv * 2 + hb;
    float o[8];
#pragma unroll
    for (int k = 0; k < 8; ++k) o[k] = w0 * ow[d0 * 8 + k];
#pragma unroll
    for (int w = 0; w < 17; ++w) {
      const int r = t + w, rx = r & 7;
      const uint4 u4 = *reinterpret_cast<const uint4*>(&KV[r * 64 + ((d0 ^ rx) << 3)]);
      float f[8]; unpack8(u4, f);
#pragma unroll
      for (int k = 0; k < 8; ++k) o[k] += s[w] * f[k];
    }
    uint4 st;
    st.x = pk2(o[0], o[1]); st.y = pk2(o[2], o[3]);
    st.z = pk2(o[4], o[5]); st.w = pk2(o[6], o[7]);
    *reinterpret_cast<uint4*>(&orow[hb * 8]) = st;
  }
}

extern "C" void kernel_launch(void* const* d_in, const int* in_sizes, int n_in,
                              void* d_out, int out_size, void* d_ws, size_t ws_size,
                              hipStream_t stream) {
  const float* x    = (const float*)d_in[0];
  const float* Wqkv = (const float*)d_in[1];
  const float* bqkv = (const float*)d_in[2];
  const float* Wout = (const float*)d_in[3];
  const float* bout = (const float*)d_in[4];
  float* out = (float*)d_out;

  const size_t SZ = (size_t)16 * T_TOT * 64;  // 4,259,840 elements
  ushort* Qb = (ushort*)d_ws;
  ushort* Kb = Qb + SZ;
  ushort* Vb = Kb + SZ;
  ushort* Xb    = Vb + SZ;
  ushort* WqkvT = Xb + SZ;
  ushort* WoutT = WqkvT + (size_t)1536 * 512;
  ushort* AObf  = WoutT + (size_t)512 * 512;

  conv_x<<<2080, 256, 0, stream>>>(x, Xb, (int)(SZ / 8));
  conv_w2<<<dim3(8, 24, 2), 256, 0, stream>>>(Wqkv, WqkvT, Wout, WoutT);
  gemm_mfma<0><<<dim3(65, 12), 256, 0, stream>>>(Xb, WqkvT, bqkv, Qb, Kb, Vb);
  fused_attn<<<1024, 256, 0, stream>>>(Qb, Kb, Vb, AObf);
  gemm_mfma<1><<<dim3(65, 8), 256, 0, stream>>>(AObf, WoutT, bout, out, nullptr, nullptr);
}

// Round 12
// 132.719 us; speedup vs baseline: 3.2653x; 1.0748x over previous
//
#include <hip/hip_runtime.h>
#include <hip/hip_bf16.h>
#include <math.h>

#define T_TOT 4160
#define H_N   8
#define NWTOK 64
#define TFEA  4096

typedef __bf16 bf16x8 __attribute__((ext_vector_type(8)));
typedef float  f32x4  __attribute__((ext_vector_type(4)));

__device__ inline ushort f2b(float f) {
  __hip_bfloat16 h = __float2bfloat16(f);
  return *reinterpret_cast<ushort*>(&h);
}
__device__ inline float b2f(ushort u) {
  union { uint i; float v; } a;
  a.i = ((uint)u) << 16;
  return a.v;
}
__device__ inline uint pk2(float a, float b) {
  return (uint)f2b(a) | ((uint)f2b(b) << 16);
}
// unpack 8 bf16 (uint4) -> 8 f32
__device__ inline void unpack8(uint4 u, float* f) {
  union { uint i; float v; } a;
  a.i = u.x << 16;        f[0] = a.v;
  a.i = u.x & 0xffff0000u; f[1] = a.v;
  a.i = u.y << 16;        f[2] = a.v;
  a.i = u.y & 0xffff0000u; f[3] = a.v;
  a.i = u.z << 16;        f[4] = a.v;
  a.i = u.z & 0xffff0000u; f[5] = a.v;
  a.i = u.w << 16;        f[6] = a.v;
  a.i = u.w & 0xffff0000u; f[7] = a.v;
}

// ---------------------------------------------------------------------------
// conv_x: fp32 -> bf16, linear. 8 elems/thread, 16B stores.
// ---------------------------------------------------------------------------
__global__ __launch_bounds__(256) void conv_x(
    const float* __restrict__ X, ushort* __restrict__ Xb, int n8) {
  const int i = blockIdx.x * 256 + threadIdx.x;
  if (i >= n8) return;
  const float4 a = reinterpret_cast<const float4*>(X)[i * 2];
  const float4 b = reinterpret_cast<const float4*>(X)[i * 2 + 1];
  union { ushort u[8]; uint4 v; } r;
  r.u[0] = f2b(a.x); r.u[1] = f2b(a.y); r.u[2] = f2b(a.z); r.u[3] = f2b(a.w);
  r.u[4] = f2b(b.x); r.u[5] = f2b(b.y); r.u[6] = f2b(b.z); r.u[7] = f2b(b.w);
  reinterpret_cast<uint4*>(Xb)[i] = r.v;
}

// ---------------------------------------------------------------------------
// conv_w2: both weight transposes in one launch (z=0: Wqkv, z=1: Wout).
// ---------------------------------------------------------------------------
__global__ __launch_bounds__(256) void conv_w2(
    const float* __restrict__ W0, ushort* __restrict__ WT0,
    const float* __restrict__ W1, ushort* __restrict__ WT1) {
  const int z = blockIdx.z;
  if (z == 1 && blockIdx.y >= 8) return;
  const float* __restrict__ W = z ? W1 : W0;
  ushort* __restrict__ WT = z ? WT1 : WT0;
  const int C = z ? 512 : 1536;
  __shared__ float tile[64][65];
  const int r0 = blockIdx.x * 64, c0 = blockIdx.y * 64;
  const int tid = threadIdx.x;
  const int rr = tid >> 4, c4 = (tid & 15) * 4;
#pragma unroll
  for (int q = 0; q < 4; ++q) {
    const int r = q * 16 + rr;
    const float4 v = *reinterpret_cast<const float4*>(&W[(size_t)(r0 + r) * C + c0 + c4]);
    tile[r][c4] = v.x; tile[r][c4 + 1] = v.y; tile[r][c4 + 2] = v.z; tile[r][c4 + 3] = v.w;
  }
  __syncthreads();
#pragma unroll
  for (int q = 0; q < 4; ++q) {
    const int cr = q * 16 + rr;
    ushort4 o;
    o.x = f2b(tile[c4][cr]);
    o.y = f2b(tile[c4 + 1][cr]);
    o.z = f2b(tile[c4 + 2][cr]);
    o.w = f2b(tile[c4 + 3][cr]);
    *reinterpret_cast<ushort4*>(&WT[(size_t)(c0 + cr) * 512 + r0 + c4]) = o;
  }
}

// ---------------------------------------------------------------------------
// gemm_mfma: C[M x N] = A[M x 512] * BT[N x 512]^T, bf16 in, f32 accum.
// 1D grid + bijective XCD-chunked swizzle (m204) with m-major work order:
// each XCD's contiguous chunk covers ~8 m-tiles x ALL n-tiles, so the
// A-panel (1 MB) and the full B (<=1.5 MB) stay L2-resident per XCD (T1).
// MODE 0: BN=128, NWG=780; qkv epilogue -> bf16 Q/K/V head layout.
// MODE 1: BN=64,  NWG=520; out epilogue -> f32 O0[m*512+n].
// ---------------------------------------------------------------------------
template<int MODE>
__global__ __launch_bounds__(256) void gemm_mfma(
    const ushort* __restrict__ A, const ushort* __restrict__ BT,
    const float* __restrict__ bias, void* __restrict__ O0v,
    void* __restrict__ O1v, void* __restrict__ O2v) {
  constexpr int BN  = (MODE == 0) ? 128 : 64;
  constexpr int NBN = (MODE == 0) ? 12 : 8;    // n-tiles
  constexpr int NWG = 65 * NBN;
  constexpr int Qc = NWG / 8, Rc = NWG % 8;
  constexpr int WN = BN / 2;
  constexpr int NJ = WN / 16;
  __shared__ ushort sA[128 * 64];
  __shared__ ushort sB[BN * 64];
  const int tid = threadIdx.x;
  const int lane = tid & 63, wave = tid >> 6;
  // bijective XCD swizzle: xcd k handles contiguous work ids
  const int bid = blockIdx.x;
  const int xcd = bid & 7, pos = bid >> 3;
  const int wg = (xcd < Rc ? xcd * (Qc + 1) : Rc * (Qc + 1) + (xcd - Rc) * Qc) + pos;
  const int m0 = (wg / NBN) * 128, n0 = (wg % NBN) * BN;
  const int wm = wave >> 1, wn = wave & 1;

  f32x4 acc[4][NJ] = {};

  auto stage = [&](int kt) {
    const ushort* Ag = A + (size_t)m0 * 512 + kt * 64;
    const ushort* Bg = BT + (size_t)n0 * 512 + kt * 64;
#pragma unroll
    for (int r = 0; r < 4; ++r) {
      const int rowbase = r * 32 + wave * 8;
      const int row = rowbase + (lane >> 3);
      const int c = lane & 7;
      const int cc = c ^ (row & 7);
      __builtin_amdgcn_global_load_lds(
          (const __attribute__((address_space(1))) void*)(Ag + (size_t)row * 512 + cc * 8),
          (__attribute__((address_space(3))) void*)(sA + rowbase * 64), 16, 0, 0);
      if (r < BN / 32)
        __builtin_amdgcn_global_load_lds(
            (const __attribute__((address_space(1))) void*)(Bg + (size_t)row * 512 + cc * 8),
            (__attribute__((address_space(3))) void*)(sB + rowbase * 64), 16, 0, 0);
    }
  };

  stage(0);
  for (int kt = 0; kt < 8; ++kt) {
    __syncthreads();
#pragma unroll
    for (int ks = 0; ks < 2; ++ks) {
      bf16x8 af[4], bfr[NJ];
      const int cc = ks * 4 + (lane >> 4);
      const int rA = wm * 64 + (lane & 15);
#pragma unroll
      for (int i = 0; i < 4; ++i) {
        const int ra = rA + i * 16;
        af[i] = *reinterpret_cast<const bf16x8*>(&sA[ra * 64 + ((cc ^ (ra & 7)) << 3)]);
      }
#pragma unroll
      for (int j = 0; j < NJ; ++j) {
        const int rb = wn * WN + j * 16 + (lane & 15);
        bfr[j] = *reinterpret_cast<const bf16x8*>(&sB[rb * 64 + ((cc ^ (rb & 7)) << 3)]);
      }
#pragma unroll
      for (int i = 0; i < 4; ++i)
#pragma unroll
        for (int j = 0; j < NJ; ++j)
          acc[i][j] = __builtin_amdgcn_mfma_f32_16x16x32_bf16(af[i], bfr[j], acc[i][j], 0, 0, 0);
    }
    __syncthreads();
    if (kt < 7) stage(kt + 1);
  }

#pragma unroll
  for (int i = 0; i < 4; ++i) {
#pragma unroll
    for (int j = 0; j < NJ; ++j) {
      const f32x4 a = acc[i][j];
      const int n = n0 + wn * WN + j * 16 + (lane & 15);
      const float bv = bias[n];
#pragma unroll
      for (int r = 0; r < 4; ++r) {
        const int m = m0 + wm * 64 + i * 16 + ((lane >> 4) << 2) + r;
        const float v = a[r] + bv;
        if (MODE == 0) {
          const int bb = m / T_TOT, t = m - bb * T_TOT;
          const int which = n >> 9, e = n & 511;
          const int h = e >> 6, d = e & 63;
          const size_t idx = ((size_t)(bb * H_N + h) * T_TOT + t) * 64 + d;
          if (which == 0)      ((ushort*)O0v)[idx] = f2b(v * 0.125f);
          else if (which == 1) ((ushort*)O1v)[idx] = f2b(v);
          else                 ((ushort*)O2v)[idx] = f2b(v);
        } else {
          ((float*)O0v)[(size_t)m * 512 + n] = v;
        }
      }
    }
  }
}

// ---------------------------------------------------------------------------
// fused_attn v3: wtok + feature local attention, MFMA scores.
// vs v2: ow LDS round-trip removed — after the 64-lane butterfly EVERY lane
// holds the wtok-PV sum for its wave's d-quarter (owq[16] in registers), and
// all later consumers (summary partial, PV rescale, output row) only touch
// their own wave's quarter. 5 barriers -> 4. Values bit-identical.
// ---------------------------------------------------------------------------
__global__ __launch_bounds__(256) void fused_attn(
    const ushort* __restrict__ Qb, const ushort* __restrict__ Kb,
    const ushort* __restrict__ Vb, ushort* __restrict__ AObf) {
  const int bh = blockIdx.x >> 6;
  const int n  = blockIdx.x & 63;
  const int tid = threadIdx.x;
  const int t  = tid & 63;   // token within chunk (== lane)
  const int wv = tid >> 6;   // wave index
  __shared__ ushort KV[80 * 64];
  __shared__ float  S[64 * 80];
  __shared__ ushort kwr[64];
  __shared__ ushort vwr[64];
  __shared__ float qw[64];
  __shared__ float ps0[4][64];
  const size_t base = (size_t)bh * T_TOT * 64;
  const int tok0 = n * 64;

  // ---- stage K window into KV (640 16B-units, swizzled dest) ----
#pragma unroll
  for (int it = 0; it < 3; ++it) {
    const int u = it * 256 + tid;
    if (u < 640) {
      const int r = u >> 3, c16 = u & 7;
      const int tok = tok0 - 8 + r;
      uint4 kv = make_uint4(0, 0, 0, 0);
      if (tok >= 0 && tok < TFEA)
        kv = *reinterpret_cast<const uint4*>(&Kb[base + (size_t)(NWTOK + tok) * 64 + c16 * 8]);
      *reinterpret_cast<uint4*>(&KV[r * 64 + ((c16 ^ (r & 7)) << 3)]) = kv;
    }
  }
  if (tid < 8)
    *reinterpret_cast<uint4*>(&kwr[tid * 8]) =
        *reinterpret_cast<const uint4*>(&Kb[base + n * 64 + tid * 8]);
  else if (tid < 16)
    *reinterpret_cast<uint4*>(&vwr[(tid - 8) * 8]) =
        *reinterpret_cast<const uint4*>(&Vb[base + n * 64 + (tid - 8) * 8]);
  else if (tid < 32) {
    const int j = tid - 16;
    const ushort4 u = *reinterpret_cast<const ushort4*>(&Qb[base + n * 64 + j * 4]);
    qw[j * 4 + 0] = b2f(u.x); qw[j * 4 + 1] = b2f(u.y);
    qw[j * 4 + 2] = b2f(u.z); qw[j * 4 + 3] = b2f(u.w);
  }
  __syncthreads();   // b1: K staged

  // ===== Phase A score part (reads KV = K) =====
  float aw_l, aw0;
  {
    const int row = t + 8, r7 = row & 7;
    float acc = 0.f, acc0 = 0.f;
#pragma unroll
    for (int g = 0; g < 8; ++g) {
      float f[8], f0[8];
      const uint4 u  = *reinterpret_cast<const uint4*>(&KV[row * 64 + ((g ^ r7) << 3)]);
      const uint4 u0 = *reinterpret_cast<const uint4*>(&kwr[g * 8]);
      unpack8(u, f); unpack8(u0, f0);
#pragma unroll
      for (int k = 0; k < 8; ++k) {
        const float qv = qw[g * 8 + k];
        acc  += qv * f[k];
        acc0 += qv * f0[k];
      }
    }
    float mx = fmaxf(acc, acc0);
#pragma unroll
    for (int off = 32; off >= 1; off >>= 1) mx = fmaxf(mx, __shfl_xor(mx, off));
    const float e = __expf(acc - mx), e0 = __expf(acc0 - mx);
    float sum = e;
#pragma unroll
    for (int off = 32; off >= 1; off >>= 1) sum += __shfl_xor(sum, off);
    sum += e0;
    aw_l = e / sum;
    aw0  = e0 / sum;
  }

  // ===== S = Q·K^T via MFMA (wave strip = tokens [wv*16, wv*16+16)) =====
  {
    f32x4 accs[5] = {};
#pragma unroll
    for (int kt = 0; kt < 2; ++kt) {
      const bf16x8 a = *reinterpret_cast<const bf16x8*>(
          &Qb[base + (size_t)(NWTOK + tok0 + wv * 16 + (t & 15)) * 64 +
              kt * 32 + ((t >> 4) << 3)]);
#pragma unroll
      for (int j = 0; j < 5; ++j) {
        const int key = j * 16 + (t & 15);
        const int koff8 = kt * 4 + (t >> 4);
        const bf16x8 b = *reinterpret_cast<const bf16x8*>(
            &KV[key * 64 + ((koff8 ^ (key & 7)) << 3)]);
        accs[j] = __builtin_amdgcn_mfma_f32_16x16x32_bf16(a, b, accs[j], 0, 0, 0);
      }
    }
#pragma unroll
    for (int j = 0; j < 5; ++j)
#pragma unroll
      for (int r = 0; r < 4; ++r)
        S[(wv * 16 + ((t >> 4) << 2) + r) * 80 + j * 16 + (t & 15)] = accs[j][r];
  }
  __syncthreads();   // b2: K reads done, S visible

  // ---- issue V loads into registers (hide under softmax) ----
  uint4 vreg0 = make_uint4(0, 0, 0, 0), vreg1 = vreg0, vreg2 = vreg0;
  {
    const int u0 = tid, u1 = 256 + tid, u2 = 512 + tid;
    { const int r = u0 >> 3, c16 = u0 & 7, tok = tok0 - 8 + r;
      if (tok >= 0 && tok < TFEA)
        vreg0 = *reinterpret_cast<const uint4*>(&Vb[base + (size_t)(NWTOK + tok) * 64 + c16 * 8]); }
    { const int r = u1 >> 3, c16 = u1 & 7, tok = tok0 - 8 + r;
      if (tok >= 0 && tok < TFEA)
        vreg1 = *reinterpret_cast<const uint4*>(&Vb[base + (size_t)(NWTOK + tok) * 64 + c16 * 8]); }
    if (u2 < 640) {
      const int r = u2 >> 3, c16 = u2 & 7, tok = tok0 - 8 + r;
      if (tok >= 0 && tok < TFEA)
        vreg2 = *reinterpret_cast<const uint4*>(&Vb[base + (size_t)(NWTOK + tok) * 64 + c16 * 8]);
    }
  }

  // ---- window softmax from S band ----
  float s[17];
  {
    const float* Srow = &S[t * 80];
    float m = -1e30f;
#pragma unroll
    for (int w = 0; w < 17; ++w) { s[w] = Srow[t + w]; m = fmaxf(m, s[w]); }
    float sum = 0.f;
#pragma unroll
    for (int w = 0; w < 17; ++w) { s[w] = __expf(s[w] - m); sum += s[w]; }
    const float inv = 1.f / sum;
#pragma unroll
    for (int w = 0; w < 17; ++w) s[w] *= inv;
  }

  // ---- write V into KV (swizzled) ----
  {
    const int u0 = tid, u1 = 256 + tid, u2 = 512 + tid;
    { const int r = u0 >> 3, c16 = u0 & 7;
      *reinterpret_cast<uint4*>(&KV[r * 64 + ((c16 ^ (r & 7)) << 3)]) = vreg0; }
    { const int r = u1 >> 3, c16 = u1 & 7;
      *reinterpret_cast<uint4*>(&KV[r * 64 + ((c16 ^ (r & 7)) << 3)]) = vreg1; }
    if (u2 < 640) {
      const int r = u2 >> 3, c16 = u2 & 7;
      *reinterpret_cast<uint4*>(&KV[r * 64 + ((c16 ^ (r & 7)) << 3)]) = vreg2;
    }
  }
  __syncthreads();   // b3: V ready

  // ===== Phase A V-part: owq = wtok PV for this wave's quarter (all lanes) =====
  float owq[16];
  {
    const int row = t + 8, r7 = row & 7;
    const float a0 = (t == 0) ? aw0 : 0.f;
#pragma unroll
    for (int hb = 0; hb < 2; ++hb) {
      const int g = wv * 2 + hb;
      float f[8], f0[8];
      const uint4 u  = *reinterpret_cast<const uint4*>(&KV[row * 64 + ((g ^ r7) << 3)]);
      const uint4 u0 = *reinterpret_cast<const uint4*>(&vwr[g * 8]);
      unpack8(u, f); unpack8(u0, f0);
#pragma unroll
      for (int k = 0; k < 8; ++k) owq[hb * 8 + k] = aw_l * f[k] + a0 * f0[k];
    }
#pragma unroll
    for (int off = 1; off < 64; off <<= 1)
#pragma unroll
      for (int k = 0; k < 16; ++k) owq[k] += __shfl_xor(owq[k], off);
    if (t == 0) {   // write the wtok output row (own quarter)
      uint4 s1, s2;
      s1.x = pk2(owq[0], owq[1]);   s1.y = pk2(owq[2], owq[3]);
      s1.z = pk2(owq[4], owq[5]);   s1.w = pk2(owq[6], owq[7]);
      s2.x = pk2(owq[8], owq[9]);   s2.y = pk2(owq[10], owq[11]);
      s2.z = pk2(owq[12], owq[13]); s2.w = pk2(owq[14], owq[15]);
      ushort* orow = &AObf[((size_t)(bh >> 3) * T_TOT + n) * 512 + (bh & 7) * 64 + wv * 16];
      *reinterpret_cast<uint4*>(&orow[0]) = s1;
      *reinterpret_cast<uint4*>(&orow[8]) = s2;
    }
  }

  // ---- summary score partial: q (this wave's d-quarter) · owq ----
  {
    float q[16];
    const ushort* qr = &Qb[base + (size_t)(NWTOK + tok0 + t) * 64 + wv * 16];
#pragma unroll
    for (int h8 = 0; h8 < 2; ++h8) {
      const uint4 u4 = *reinterpret_cast<const uint4*>(&qr[h8 * 8]);
      unpack8(u4, &q[h8 * 8]);
    }
    float acc = 0.f;
#pragma unroll
    for (int k = 0; k < 16; ++k) acc += q[k] * owq[k];
    ps0[wv][t] = acc;
  }
  __syncthreads();   // b4: ps0 ready

  float s0 = ps0[0][t] + ps0[1][t] + ps0[2][t] + ps0[3][t];
  float mx = s0;
#pragma unroll
  for (int off = 32; off >= 1; off >>= 1) mx = fmaxf(mx, __shfl_xor(mx, off));
  const float e0 = __expf(s0 - mx);
  float es = e0;
#pragma unroll
  for (int off = 32; off >= 1; off >>= 1) es += __shfl_xor(es, off);
  const float w0 = e0 / es;

  // ===== PV for this wave's 16 dims (reads KV = V) =====
  const int bb = bh >> 3, h = bh & 7;
  ushort* orow = &AObf[((size_t)bb * T_TOT + NWTOK + tok0 + t) * 512 + h * 64 + wv * 16];
#pragma unroll
  for (int hb = 0; hb < 2; ++hb) {
    const int d0 = wv * 2 + hb;
    float o[8];
#pragma unroll
    for (int k = 0; k < 8; ++k) o[k] = w0 * owq[hb * 8 + k];
#pragma unroll
    for (int w = 0; w < 17; ++w) {
      const int r = t + w, rx = r & 7;
      const uint4 u4 = *reinterpret_cast<const uint4*>(&KV[r * 64 + ((d0 ^ rx) << 3)]);
      float f[8]; unpack8(u4, f);
#pragma unroll
      for (int k = 0; k < 8; ++k) o[k] += s[w] * f[k];
    }
    uint4 st;
    st.x = pk2(o[0], o[1]); st.y = pk2(o[2], o[3]);
    st.z = pk2(o[4], o[5]); st.w = pk2(o[6], o[7]);
    *reinterpret_cast<uint4*>(&orow[hb * 8]) = st;
  }
}

extern "C" void kernel_launch(void* const* d_in, const int* in_sizes, int n_in,
                              void* d_out, int out_size, void* d_ws, size_t ws_size,
                              hipStream_t stream) {
  const float* x    = (const float*)d_in[0];
  const float* Wqkv = (const float*)d_in[1];
  const float* bqkv = (const float*)d_in[2];
  const float* Wout = (const float*)d_in[3];
  const float* bout = (const float*)d_in[4];
  float* out = (float*)d_out;

  const size_t SZ = (size_t)16 * T_TOT * 64;  // 4,259,840 elements
  ushort* Qb = (ushort*)d_ws;
  ushort* Kb = Qb + SZ;
  ushort* Vb = Kb + SZ;
  ushort* Xb    = Vb + SZ;
  ushort* WqkvT = Xb + SZ;
  ushort* WoutT = WqkvT + (size_t)1536 * 512;
  ushort* AObf  = WoutT + (size_t)512 * 512;

  conv_x<<<2080, 256, 0, stream>>>(x, Xb, (int)(SZ / 8));
  conv_w2<<<dim3(8, 24, 2), 256, 0, stream>>>(Wqkv, WqkvT, Wout, WoutT);
  gemm_mfma<0><<<780, 256, 0, stream>>>(Xb, WqkvT, bqkv, Qb, Kb, Vb);
  fused_attn<<<1024, 256, 0, stream>>>(Qb, Kb, Vb, AObf);
  gemm_mfma<1><<<520, 256, 0, stream>>>(AObf, WoutT, bout, out, nullptr, nullptr);
}